// Round 3
// 193.609 us; speedup vs baseline: 1.0323x; 1.0323x over previous
//
#include <hip/hip_runtime.h>

#define NT 1024      // N_TOPICS
#define TD 128       // TOPIC_DIM
#define HID 512      // HIDDEN
#define NH 8         // N_HEADS
#define HD 64        // HEAD_DIM
#define NB 8         // BATCH

typedef unsigned short us;
typedef _Float16 h16;
typedef h16 half8 __attribute__((ext_vector_type(8)));
typedef h16 h16x2 __attribute__((ext_vector_type(2)));
typedef float f32x4 __attribute__((ext_vector_type(4)));

#define LOG2E 1.44269504f

extern "C" __device__ _Float16 __ocml_exp2_f16(_Float16);

__device__ __forceinline__ us f2h(float x) { return __builtin_bit_cast(us, (h16)x); }
__device__ __forceinline__ float h2f(us s) { return (float)__builtin_bit_cast(h16, s); }
// pack two f32 -> two f16 in one v_cvt_pkrtz_f16_f32
__device__ __forceinline__ unsigned int pkh2(float a, float b) {
    auto v = __builtin_amdgcn_cvt_pkrtz(a, b);
    return __builtin_bit_cast(unsigned int, v);
}

// ============ kprep: kmax (0-1023) | node0 MFMA GEMM (1024-1151) | gW transpose (1152-1279)
//              block 1152 also initializes out[b] = fc2b[0] for khead2's atomics
__global__ __launch_bounds__(256) void kprep(const float* __restrict__ tm, float* __restrict__ part,
                                             const float* __restrict__ emb, const float* __restrict__ sW,
                                             const float* __restrict__ sb, us* __restrict__ node0b,
                                             const float* __restrict__ gW, us* __restrict__ Wt,
                                             const float* __restrict__ fc2b, float* __restrict__ out) {
    __shared__ __align__(16) float smf[8768];   // 35 KB shared by branches
    int bx = blockIdx.x, t = threadIdx.x;
    if (bx < 1024) {
        const float4* tm4 = (const float4*)tm;
        size_t base = (size_t)bx * 256 + t;
        float m = -1e30f;
        #pragma unroll
        for (int k = 0; k < 8; k++) {
            float4 v = tm4[base + (size_t)k * 262144];
            m = fmaxf(m, fmaxf(fmaxf(v.x, v.y), fmaxf(v.z, v.w)));
        }
        smf[t] = m; __syncthreads();
        for (int s = 128; s > 0; s >>= 1) { if (t < s) smf[t] = fmaxf(smf[t], smf[t + s]); __syncthreads(); }
        if (t == 0) part[bx] = smf[0];
    } else if (bx < 1152) {
        // node0 = emb @ sW^T + sb via MFMA. block: (iblk 16) x (oseg 8); K=128, one barrier.
        int g = bx - 1024; int iblk = g & 15, oseg = g >> 4;
        us* As = (us*)smf;              // [64][136]
        us* Bs = (us*)smf + 64 * 136;   // [64][136]
        const float4* esrc = (const float4*)(emb + (size_t)iblk * 64 * TD);
        const float4* wsrc = (const float4*)(sW + (size_t)oseg * 64 * TD);
        #pragma unroll
        for (int rep = 0; rep < 8; rep++) {
            int f = rep * 256 + t;
            int row = f >> 5, c4 = f & 31;
            float4 av = esrc[f];
            float4 bv = wsrc[f];
            uint2 pa, pb;
            pa.x = pkh2(av.x, av.y); pa.y = pkh2(av.z, av.w);
            pb.x = pkh2(bv.x, bv.y); pb.y = pkh2(bv.z, bv.w);
            *(uint2*)&As[row * 136 + c4 * 4] = pa;
            *(uint2*)&Bs[row * 136 + c4 * 4] = pb;
        }
        __syncthreads();
        int l = t & 63, w = t >> 6, m = l & 15, q = l >> 4;
        f32x4 acc[4];
        #pragma unroll
        for (int ot = 0; ot < 4; ot++) acc[ot] = (f32x4){0.f, 0.f, 0.f, 0.f};
        #pragma unroll
        for (int ks = 0; ks < 4; ks++) {
            half8 a = *(const half8*)&As[(w * 16 + m) * 136 + ks * 32 + q * 8];
            #pragma unroll
            for (int ot = 0; ot < 4; ot++) {
                half8 b = *(const half8*)&Bs[(ot * 16 + m) * 136 + ks * 32 + q * 8];
                acc[ot] = __builtin_amdgcn_mfma_f32_16x16x32_f16(a, b, acc[ot], 0, 0, 0);
            }
        }
        #pragma unroll
        for (int ot = 0; ot < 4; ot++) {
            int col = oseg * 64 + ot * 16 + m;
            float sbv = sb[col];
            #pragma unroll
            for (int rr = 0; rr < 4; rr++) {
                int rowi = iblk * 64 + w * 16 + q * 4 + rr;
                node0b[(size_t)rowi * HID + col] = f2h(acc[ot][rr] + sbv);
            }
        }
    } else {
        // Wt[lh][o][k] = f16(gW[lh][k][o]) via LDS tile transpose
        int g = bx - 1152; int lh = g >> 3, kt = g & 7;
        if (g == 0 && t < NB) out[t] = fc2b[0];   // init for khead2 atomics
        float* tile = smf;   // [64][65]
        const float4* src = (const float4*)(gW + ((size_t)lh * HID + kt * 64) * HD);
        #pragma unroll
        for (int rep = 0; rep < 4; rep++) {
            int f = rep * 256 + t;
            float4 v = src[f];
            int row = f >> 4, col = (f & 15) * 4;
            float* d = tile + row * 65 + col;
            d[0] = v.x; d[1] = v.y; d[2] = v.z; d[3] = v.w;
        }
        __syncthreads();
        int o = t >> 2, ks = (t & 3) * 16;
        us pk[16];
        #pragma unroll
        for (int j = 0; j < 16; j++) pk[j] = f2h(tile[(ks + j) * 65 + o]);
        us* dst = Wt + (size_t)lh * HD * HID + (size_t)o * HID + kt * 64 + ks;
        *(uint4*)dst = *(uint4*)pk;
        *(uint4*)(dst + 8) = *(uint4*)&pk[8];
    }
}

// ============ shared GEMM body: 64x64 tile, BK=64, dbuf, distance-2 global pipeline =====
__device__ __forceinline__ void gemm_body(const us* __restrict__ A, const us* __restrict__ W,
                                          const float* __restrict__ gav,
                                          us* __restrict__ outT, us* __restrict__ outR,
                                          float* __restrict__ esO, float* __restrict__ edO,
                                          int iblk, int b, int h, int t, us* sm) {
    us* As = sm;              // [2][64*72]
    us* Bs = sm + 2 * 4608;   // [2][64*72]
    int row = t >> 2, ks = t & 3;
    int l = t & 63, w = t >> 6, m = l & 15, q = l >> 4;
    size_t arow0 = (size_t)(b * NT + iblk * 64);
    const us* ar = A + (arow0 + row) * HID + ks * 16;
    const us* br = W + ((size_t)(h * HD + row)) * HID + ks * 16;
    f32x4 acc[4];
    #pragma unroll
    for (int ot = 0; ot < 4; ot++) acc[ot] = (f32x4){0.f, 0.f, 0.f, 0.f};
    {
        uint4 x0 = *(const uint4*)ar, x1 = *(const uint4*)(ar + 8);
        uint4 y0 = *(const uint4*)br, y1 = *(const uint4*)(br + 8);
        *(uint4*)&As[row * 72 + ks * 16] = x0; *(uint4*)&As[row * 72 + ks * 16 + 8] = x1;
        *(uint4*)&Bs[row * 72 + ks * 16] = y0; *(uint4*)&Bs[row * 72 + ks * 16 + 8] = y1;
    }
    uint4 a0 = *(const uint4*)(ar + 64), a1 = *(const uint4*)(ar + 72);
    uint4 b0 = *(const uint4*)(br + 64), b1 = *(const uint4*)(br + 72);
    for (int it = 0; it < 8; it++) {
        int cur = it & 1, nxt = cur ^ 1;
        uint4 na0, na1, nb0, nb1;
        if (it < 6) {
            int k0 = (it + 2) * 64;
            na0 = *(const uint4*)(ar + k0); na1 = *(const uint4*)(ar + k0 + 8);
            nb0 = *(const uint4*)(br + k0); nb1 = *(const uint4*)(br + k0 + 8);
        }
        __syncthreads();
        if (it < 7) {
            *(uint4*)&As[nxt * 4608 + row * 72 + ks * 16] = a0;
            *(uint4*)&As[nxt * 4608 + row * 72 + ks * 16 + 8] = a1;
            *(uint4*)&Bs[nxt * 4608 + row * 72 + ks * 16] = b0;
            *(uint4*)&Bs[nxt * 4608 + row * 72 + ks * 16 + 8] = b1;
        }
        const us* Ac = As + cur * 4608; const us* Bc = Bs + cur * 4608;
        #pragma unroll
        for (int kt = 0; kt < 2; kt++) {
            half8 av = *(const half8*)&Ac[(w * 16 + m) * 72 + kt * 32 + q * 8];
            #pragma unroll
            for (int ot = 0; ot < 4; ot++) {
                half8 bv = *(const half8*)&Bc[(ot * 16 + m) * 72 + kt * 32 + q * 8];
                acc[ot] = __builtin_amdgcn_mfma_f32_16x16x32_f16(av, bv, acc[ot], 0, 0, 0);
            }
        }
        if (it < 6) { a0 = na0; a1 = na1; b0 = nb0; b1 = nb1; }
    }
    const float* gas = gav + h * 2 * HD;
    float gs[4], gd[4];
    #pragma unroll
    for (int ot = 0; ot < 4; ot++) { gs[ot] = gas[ot * 16 + m]; gd[ot] = gas[HD + ot * 16 + m]; }
    size_t ebase = ((size_t)b * NH + h) * NT + iblk * 64;
    #pragma unroll
    for (int rr = 0; rr < 4; rr++) {
        float s = 0.f, d = 0.f;
        #pragma unroll
        for (int ot = 0; ot < 4; ot++) { float v = acc[ot][rr]; s = fmaf(v, gs[ot], s); d = fmaf(v, gd[ot], d); }
        #pragma unroll
        for (int mask = 1; mask < 16; mask <<= 1) { s += __shfl_xor(s, mask); d += __shfl_xor(d, mask); }
        if (m == 0) {
            int rowi = w * 16 + q * 4 + rr;
            esO[ebase + rowi] = s;
            edO[ebase + rowi] = d;
        }
    }
    #pragma unroll
    for (int ot = 0; ot < 4; ot++) {
        int col = h * HD + ot * 16 + m;
        #pragma unroll
        for (int rr = 0; rr < 4; rr++) {
            int i_loc = w * 16 + q * 4 + rr;
            float v = acc[ot][rr];
            if (outT) outT[(size_t)col * NT + iblk * 64 + i_loc] = f2h(v);
            if (outR) outR[(arow0 + i_loc) * HID + col] = f2h(v);
        }
    }
}

// ============ kphase1: ktw (0-2047, tw*log2e or NaN, f16) | layer-1 GEMM (2048-2175) ====
__global__ __launch_bounds__(256) void kphase1(const float* __restrict__ tm, const int* __restrict__ adj,
                                               const float* __restrict__ part, us* __restrict__ TWb,
                                               const us* __restrict__ node0b, const us* __restrict__ Wt,
                                               const float* __restrict__ ga, us* __restrict__ Ht1,
                                               float* __restrict__ es1, float* __restrict__ ed1) {
    __shared__ __align__(16) us sm[4 * 4608];
    int bx = blockIdx.x, t = threadIdx.x;
    if (bx < 2048) {
        float* red = (float*)sm;
        float m = fmaxf(fmaxf(part[t * 4], part[t * 4 + 1]), fmaxf(part[t * 4 + 2], part[t * 4 + 3]));
        red[t] = m; __syncthreads();
        for (int s = 128; s > 0; s >>= 1) { if (t < s) red[t] = fmaxf(red[t], red[t + s]); __syncthreads(); }
        float tmx = red[0];
        const float C = 0.1f * LOG2E;
        const float NANF = __uint_as_float(0x7FC00000u);
        #pragma unroll
        for (int it = 0; it < 4; it++) {
            size_t idx = (((size_t)bx * 4 + it) * 256 + t) * 4;
            float4 tv = *(const float4*)(tm + idx);
            int4 av = *(const int4*)(adj + idx);
            float w0 = exp2f((tv.x - tmx) * C) * LOG2E;
            float w1 = exp2f((tv.y - tmx) * C) * LOG2E;
            float w2 = exp2f((tv.z - tmx) * C) * LOG2E;
            float w3 = exp2f((tv.w - tmx) * C) * LOG2E;
            w0 = av.x ? w0 : NANF;   // NaN when masked
            w1 = av.y ? w1 : NANF;
            w2 = av.z ? w2 : NANF;
            w3 = av.w ? w3 : NANF;
            uint2 pk;
            pk.x = pkh2(w0, w1);
            pk.y = pkh2(w2, w3);
            *(uint2*)&TWb[idx] = pk;
        }
    } else {
        int g = bx - 2048;
        gemm_body(node0b, Wt, ga, Ht1, nullptr, es1, ed1, g & 15, 0, g >> 4, t, sm);
    }
}

// ============ kedge: E1[h][i][j] = f16(leaky(es1_i + ed1_j)), batch-invariant ===========
__global__ __launch_bounds__(256) void kedge(const float* __restrict__ es, const float* __restrict__ ed,
                                             us* __restrict__ E1) {
    int g = blockIdx.x;             // 2048: h = g>>8, 4 i-rows per block
    int h = g >> 8, i0 = (g & 255) << 2;
    int t = threadIdx.x;
    __shared__ float eds[NT];
    *(float4*)&eds[t * 4] = *(const float4*)&ed[h * NT + t * 4];
    __syncthreads();
    int j = t * 4;
    float4 e4 = *(const float4*)&eds[j];
    #pragma unroll
    for (int r = 0; r < 4; r++) {
        float esv = es[h * NT + i0 + r];
        float a = esv + e4.x; a = fmaxf(a, 0.2f * a);
        float bq = esv + e4.y; bq = fmaxf(bq, 0.2f * bq);
        float c = esv + e4.z; c = fmaxf(c, 0.2f * c);
        float d = esv + e4.w; d = fmaxf(d, 0.2f * d);
        uint2 pk;
        pk.x = pkh2(a, bq);
        pk.y = pkh2(c, d);
        *(uint2*)&E1[((size_t)(h * NT) + i0 + r) * NT + j] = pk;
    }
}

// ============ layer-2 GEMM =============================================================
__global__ __launch_bounds__(256) void kgemm2(const us* __restrict__ node1b, const us* __restrict__ Wt2,
                                              const float* __restrict__ ga2, us* __restrict__ H2b,
                                              float* __restrict__ es2, float* __restrict__ ed2) {
    __shared__ __align__(16) us sm[4 * 4608];
    int x = blockIdx.x;
    gemm_body(node1b, Wt2, ga2, nullptr, H2b, es2, ed2, x & 15, x >> 4, blockIdx.y, threadIdx.x, sm);
}

// ============ layer-1 attention: P = max(exp2(tw*E),0) in packed fp16, ones-MFMA denom ==
__device__ __forceinline__ unsigned int p_word(unsigned int tw, unsigned int ev) {
    h16x2 t = __builtin_bit_cast(h16x2, tw);
    h16x2 e = __builtin_bit_cast(h16x2, ev);
    h16x2 m = t * e;                          // v_pk_mul_f16; NaN tw -> NaN
    h16x2 p;
    p.x = __ocml_exp2_f16(m.x);               // v_exp_f16
    p.y = __ocml_exp2_f16(m.y);
    h16x2 z = {(h16)0.0f, (h16)0.0f};
    h16x2 r = __builtin_elementwise_max(p, z); // v_pk_max_f16 (maxNum): NaN -> 0
    return __builtin_bit_cast(unsigned int, r);
}

__device__ __forceinline__ void compute_p(uint4 T0, uint4 T1, uint4 E0, uint4 E1v,
                                          uint4& P01, uint4& P23) {
    P01.x = p_word(T0.x, E0.x);
    P01.y = p_word(T0.y, E0.y);
    P01.z = p_word(T0.z, E0.z);
    P01.w = p_word(T0.w, E0.w);
    P23.x = p_word(T1.x, E1v.x);
    P23.y = p_word(T1.y, E1v.y);
    P23.z = p_word(T1.z, E1v.z);
    P23.w = p_word(T1.w, E1v.w);
}

__global__ __launch_bounds__(256) void kattn1(const us* __restrict__ TWb, const us* __restrict__ Ht,
                                              const us* __restrict__ E1, us* __restrict__ node1b) {
    int x = blockIdx.x; int iblk = x & 15; int b = x >> 4; int h = blockIdx.y;
    int t = threadIdx.x;
    __shared__ __align__(16) us Ps[2 * 4608];
    __shared__ __align__(16) us Hs[2 * 4608];
    __shared__ float invl_s[64];
    int i = t >> 2, js = t & 3;
    int l = t & 63, w = t >> 6, m = l & 15, q = l >> 4;
    const us* twrow = TWb + ((size_t)(b * NT) + iblk * 64 + i) * NT + js * 16;
    const us* erow  = E1 + ((size_t)(h * NT) + iblk * 64 + i) * NT + js * 16;
    const us* htrow = Ht + ((size_t)(h * HD) + i) * NT + js * 16;
    f32x4 acc[4];
    #pragma unroll
    for (int ot = 0; ot < 4; ot++) acc[ot] = (f32x4){0.f, 0.f, 0.f, 0.f};
    f32x4 acc1 = (f32x4){0.f, 0.f, 0.f, 0.f};         // ones-column: row sums of P
    h16 ov = (m == 0) ? (h16)1.0f : (h16)0.0f;         // B[k][0]=1 else 0
    half8 bones = {ov, ov, ov, ov, ov, ov, ov, ov};
    uint4 T0, T1, E0, E1r, Hh0, Hh1;
    T0 = *(const uint4*)twrow; T1 = *(const uint4*)(twrow + 8);
    E0 = *(const uint4*)erow;  E1r = *(const uint4*)(erow + 8);
    Hh0 = *(const uint4*)htrow; Hh1 = *(const uint4*)(htrow + 8);
    {
        uint4 p01, p23;
        compute_p(T0, T1, E0, E1r, p01, p23);
        us* Pd = Ps + i * 72 + js * 16;
        us* Hd = Hs + i * 72 + js * 16;
        *(uint4*)Pd = p01; *(uint4*)(Pd + 8) = p23;
        *(uint4*)Hd = Hh0; *(uint4*)(Hd + 8) = Hh1;
    }
    T0 = *(const uint4*)(twrow + 64); T1 = *(const uint4*)(twrow + 72);
    E0 = *(const uint4*)(erow + 64);  E1r = *(const uint4*)(erow + 72);
    Hh0 = *(const uint4*)(htrow + 64); Hh1 = *(const uint4*)(htrow + 72);
    for (int it = 0; it < 16; it++) {
        int cur = it & 1, nxt = cur ^ 1;
        uint4 nT0, nT1, nE0, nE1, nH0, nH1;
        if (it < 14) {
            int j0 = (it + 2) * 64;
            nT0 = *(const uint4*)(twrow + j0); nT1 = *(const uint4*)(twrow + j0 + 8);
            nE0 = *(const uint4*)(erow + j0);  nE1 = *(const uint4*)(erow + j0 + 8);
            nH0 = *(const uint4*)(htrow + j0); nH1 = *(const uint4*)(htrow + j0 + 8);
        }
        uint4 p01, p23;
        if (it < 15) compute_p(T0, T1, E0, E1r, p01, p23);
        __syncthreads();
        if (it < 15) {
            us* Pd = Ps + nxt * 4608 + i * 72 + js * 16;
            us* Hd = Hs + nxt * 4608 + i * 72 + js * 16;
            *(uint4*)Pd = p01; *(uint4*)(Pd + 8) = p23;
            *(uint4*)Hd = Hh0; *(uint4*)(Hd + 8) = Hh1;
        }
        const us* Pc = Ps + cur * 4608; const us* Hc = Hs + cur * 4608;
        #pragma unroll
        for (int kt = 0; kt < 2; kt++) {
            half8 av = *(const half8*)&Pc[(w * 16 + m) * 72 + kt * 32 + q * 8];
            #pragma unroll
            for (int ot = 0; ot < 4; ot++) {
                half8 bv = *(const half8*)&Hc[(ot * 16 + m) * 72 + kt * 32 + q * 8];
                acc[ot] = __builtin_amdgcn_mfma_f32_16x16x32_f16(av, bv, acc[ot], 0, 0, 0);
            }
            acc1 = __builtin_amdgcn_mfma_f32_16x16x32_f16(av, bones, acc1, 0, 0, 0);
        }
        if (it < 14) { T0 = nT0; T1 = nT1; E0 = nE0; E1r = nE1; Hh0 = nH0; Hh1 = nH1; }
    }
    if (m == 0) {
        #pragma unroll
        for (int rr = 0; rr < 4; rr++) invl_s[w * 16 + q * 4 + rr] = 1.f / acc1[rr];
    }
    __syncthreads();
    #pragma unroll
    for (int ot = 0; ot < 4; ot++) {
        int col = h * HD + ot * 16 + m;
        #pragma unroll
        for (int rr = 0; rr < 4; rr++) {
            int i_loc = w * 16 + q * 4 + rr;
            float v = acc[ot][rr] * invl_s[i_loc];
            v = v > 0.f ? v : (__expf(v) - 1.f);  // ELU
            node1b[(size_t)(b * NT + iblk * 64 + i_loc) * HID + col] = f2h(v);
        }
    }
}

// ============ layer-2 attention phase A: partial PV over 64-j slices (1024 blocks) ======
__global__ __launch_bounds__(256) void kattn2a(const us* __restrict__ TWb, const us* __restrict__ H2b,
                                               const float* __restrict__ es2, const float* __restrict__ ed2,
                                               const int* __restrict__ topic_ids,
                                               float* __restrict__ ppv, float* __restrict__ pl) {
    int js = blockIdx.x, h = blockIdx.y, b = blockIdx.z;
    int t = threadIdx.x;
    __shared__ float pls[64];
    __shared__ float red[256];
    int qi = topic_ids[b];
    if (t < 64) {
        int j = js * 64 + t;
        float esq = es2[((size_t)b * NH + h) * NT + qi];
        float tw = h2f(TWb[((size_t)(b * NT) + qi) * NT + j]);  // tw*log2e or NaN
        float e = esq + ed2[((size_t)b * NH + h) * NT + j];
        e = fmaxf(e, 0.2f * e) * tw;
        float p = fmaxf(exp2f(e), 0.f);   // NaN -> 0
        pls[t] = p;
        float lsum = p;
        #pragma unroll
        for (int mask = 1; mask < 64; mask <<= 1) lsum += __shfl_xor(lsum, mask);
        if (t == 0) pl[((size_t)b * NH + h) * 16 + js] = lsum;
    }
    __syncthreads();
    int o = t & 63, jg = t >> 6;
    float acc = 0.f;
    const us* hb = H2b + ((size_t)(b * NT) + js * 64 + jg * 16) * HID + h * HD + o;
    #pragma unroll
    for (int jj = 0; jj < 16; jj++)
        acc = fmaf(pls[jg * 16 + jj], h2f(hb[(size_t)jj * HID]), acc);
    red[t] = acc; __syncthreads();
    if (t < 64) {
        float pv = red[t] + red[t + 64] + red[t + 128] + red[t + 192];
        ppv[(((size_t)b * NH + h) * 16 + js) * HD + t] = pv;
    }
}

// ============ khead2: 256 blocks (kseg 32 x b 8); atomicAdd partials into out[b] ========
__global__ __launch_bounds__(256) void khead2(const float* __restrict__ ppv, const float* __restrict__ pl,
                                              const float* __restrict__ attr,
                                              const float* __restrict__ aW, const float* __restrict__ ab,
                                              const float* __restrict__ fc1W, const float* __restrict__ fc1b,
                                              const float* __restrict__ fc2W, float* __restrict__ out) {
    int kseg = blockIdx.x, b = blockIdx.y;
    int t = threadIdx.x;
    __shared__ float comb[HID];
    __shared__ float linv[NH];
    __shared__ float r2[256];
    if (t < NH) {
        float lsum = 0.f;
        #pragma unroll
        for (int js = 0; js < 16; js++) lsum += pl[((size_t)b * NH + t) * 16 + js];
        linv[t] = 1.f / lsum;
    }
    __syncthreads();
    float av = attr[b];
    for (int k = t; k < HID; k += 256) {
        int h = k >> 6, o = k & 63;
        float pv = 0.f;
        #pragma unroll
        for (int js = 0; js < 16; js++) pv += ppv[(((size_t)b * NH + h) * 16 + js) * HD + o];
        float v = pv * linv[h];
        v = v > 0.f ? v : (__expf(v) - 1.f);  // ELU
        comb[k] = v + av * aW[k] + ab[k];
    }
    __syncthreads();
    // 16 fc1 rows per block; 16 threads per row, coalesced scalar reads
    int kk = kseg * 16 + (t >> 4);
    int j = t & 15;
    const float* row = fc1W + (size_t)kk * HID;
    float acc = 0.f;
    #pragma unroll 8
    for (int mi = 0; mi < 32; mi++) {
        int idx = mi * 16 + j;
        acc = fmaf(comb[idx], row[idx], acc);
    }
    #pragma unroll
    for (int mask = 1; mask < 16; mask <<= 1) acc += __shfl_xor(acc, mask);
    float partv = 0.f;
    if (j == 0) {
        float hk = fmaxf(acc + fc1b[kk], 0.f);
        partv = hk * fc2W[kk];
    }
    r2[t] = partv; __syncthreads();
    for (int s = 128; s > 0; s >>= 1) { if (t < s) r2[t] += r2[t + s]; __syncthreads(); }
    if (t == 0) atomicAdd(&out[b], r2[0]);
}

extern "C" void kernel_launch(void* const* d_in, const int* in_sizes, int n_in,
                              void* d_out, int out_size, void* d_ws, size_t ws_size,
                              hipStream_t stream) {
    const int*   topic_ids = (const int*)d_in[0];
    const int*   adj       = (const int*)d_in[1];
    const float* tm        = (const float*)d_in[2];
    const float* attr      = (const float*)d_in[3];
    const float* emb       = (const float*)d_in[4];
    const float* sW        = (const float*)d_in[5];
    const float* sb        = (const float*)d_in[6];
    const float* aW        = (const float*)d_in[7];
    const float* ab        = (const float*)d_in[8];
    const float* gW        = (const float*)d_in[9];   // (2,8,512,64)
    const float* ga        = (const float*)d_in[10];  // (2,8,128,1)
    const float* fc1W      = (const float*)d_in[11];
    const float* fc1b      = (const float*)d_in[12];
    const float* fc2W      = (const float*)d_in[13];
    const float* fc2b      = (const float*)d_in[14];
    float* out = (float*)d_out;

    char* p = (char*)d_ws;
    us* TWb    = (us*)p; p += sizeof(us) * (size_t)NB * NT * NT;        // 16.8 MB
    us* E1     = (us*)p; p += sizeof(us) * (size_t)NH * NT * NT;        // 16.8 MB
    us* node0b = (us*)p; p += sizeof(us) * (size_t)NT * HID;            // 1 MB
    us* Wt     = (us*)p; p += sizeof(us) * (size_t)2 * NH * HD * HID;   // 1 MB
    us* Ht1    = (us*)p; p += sizeof(us) * (size_t)HID * NT;            // 1 MB
    us* node1b = (us*)p; p += sizeof(us) * (size_t)NB * NT * HID;       // 8 MB
    us* H2b    = (us*)p; p += sizeof(us) * (size_t)NB * NT * HID;       // 8 MB
    float* es1  = (float*)p; p += sizeof(float) * NH * NT;
    float* ed1  = (float*)p; p += sizeof(float) * NH * NT;
    float* es2  = (float*)p; p += sizeof(float) * NB * NH * NT;
    float* ed2  = (float*)p; p += sizeof(float) * NB * NH * NT;
    float* ppv  = (float*)p; p += sizeof(float) * NB * NH * 16 * HD;
    float* pl   = (float*)p; p += sizeof(float) * NB * NH * 16;
    float* part = (float*)p; p += sizeof(float) * 1024;

    kprep<<<1280, 256, 0, stream>>>(tm, part, emb, sW, sb, node0b, gW, Wt, fc2b, out);
    kphase1<<<2176, 256, 0, stream>>>(tm, adj, part, TWb, node0b, Wt, ga, Ht1, es1, ed1);
    kedge<<<2048, 256, 0, stream>>>(es1, ed1, E1);
    kattn1<<<dim3(16 * NB, NH), 256, 0, stream>>>(TWb, Ht1, E1, node1b);
    kgemm2<<<dim3(16 * NB, NH), 256, 0, stream>>>(node1b, Wt + (size_t)NH * HD * HID,
                                                  ga + NH * 2 * HD, H2b, es2, ed2);
    kattn2a<<<dim3(16, NH, NB), 256, 0, stream>>>(TWb, H2b, es2, ed2, topic_ids, ppv, pl);
    khead2<<<dim3(32, NB), 256, 0, stream>>>(ppv, pl, attr, aW, ab, fc1W, fc1b, fc2W, out);
}

// Round 4
// 187.907 us; speedup vs baseline: 1.0636x; 1.0303x over previous
//
#include <hip/hip_runtime.h>

#define NT 1024      // N_TOPICS
#define TD 128       // TOPIC_DIM
#define HID 512      // HIDDEN
#define NH 8         // N_HEADS
#define HD 64        // HEAD_DIM
#define NB 8         // BATCH

typedef unsigned short us;
typedef _Float16 h16;
typedef h16 half8 __attribute__((ext_vector_type(8)));
typedef h16 h16x2 __attribute__((ext_vector_type(2)));
typedef float f32x4 __attribute__((ext_vector_type(4)));

#define LOG2E 1.44269504f

extern "C" __device__ _Float16 __ocml_exp2_f16(_Float16);

__device__ __forceinline__ us f2h(float x) { return __builtin_bit_cast(us, (h16)x); }
__device__ __forceinline__ float h2f(us s) { return (float)__builtin_bit_cast(h16, s); }
// pack two f32 -> two f16 in one v_cvt_pkrtz_f16_f32
__device__ __forceinline__ unsigned int pkh2(float a, float b) {
    auto v = __builtin_amdgcn_cvt_pkrtz(a, b);
    return __builtin_bit_cast(unsigned int, v);
}

// ============ kprep: kmax (0-1023) | node0 MFMA GEMM (1024-1151) | gW transpose (1152-1279)
//              block 1152 also initializes out[b] = fc2b[0] for khead2's atomics
__global__ __launch_bounds__(256) void kprep(const float* __restrict__ tm, float* __restrict__ part,
                                             const float* __restrict__ emb, const float* __restrict__ sW,
                                             const float* __restrict__ sb, us* __restrict__ node0b,
                                             const float* __restrict__ gW, us* __restrict__ Wt,
                                             const float* __restrict__ fc2b, float* __restrict__ out) {
    __shared__ __align__(16) float smf[8768];   // 35 KB shared by branches
    int bx = blockIdx.x, t = threadIdx.x;
    if (bx < 1024) {
        const float4* tm4 = (const float4*)tm;
        size_t base = (size_t)bx * 256 + t;
        float m = -1e30f;
        #pragma unroll
        for (int k = 0; k < 8; k++) {
            float4 v = tm4[base + (size_t)k * 262144];
            m = fmaxf(m, fmaxf(fmaxf(v.x, v.y), fmaxf(v.z, v.w)));
        }
        smf[t] = m; __syncthreads();
        for (int s = 128; s > 0; s >>= 1) { if (t < s) smf[t] = fmaxf(smf[t], smf[t + s]); __syncthreads(); }
        if (t == 0) part[bx] = smf[0];
    } else if (bx < 1152) {
        // node0 = emb @ sW^T + sb via MFMA. block: (iblk 16) x (oseg 8); K=128, one barrier.
        int g = bx - 1024; int iblk = g & 15, oseg = g >> 4;
        us* As = (us*)smf;              // [64][136]
        us* Bs = (us*)smf + 64 * 136;   // [64][136]
        const float4* esrc = (const float4*)(emb + (size_t)iblk * 64 * TD);
        const float4* wsrc = (const float4*)(sW + (size_t)oseg * 64 * TD);
        #pragma unroll
        for (int rep = 0; rep < 8; rep++) {
            int f = rep * 256 + t;
            int row = f >> 5, c4 = f & 31;
            float4 av = esrc[f];
            float4 bv = wsrc[f];
            uint2 pa, pb;
            pa.x = pkh2(av.x, av.y); pa.y = pkh2(av.z, av.w);
            pb.x = pkh2(bv.x, bv.y); pb.y = pkh2(bv.z, bv.w);
            *(uint2*)&As[row * 136 + c4 * 4] = pa;
            *(uint2*)&Bs[row * 136 + c4 * 4] = pb;
        }
        __syncthreads();
        int l = t & 63, w = t >> 6, m = l & 15, q = l >> 4;
        f32x4 acc[4];
        #pragma unroll
        for (int ot = 0; ot < 4; ot++) acc[ot] = (f32x4){0.f, 0.f, 0.f, 0.f};
        #pragma unroll
        for (int ks = 0; ks < 4; ks++) {
            half8 a = *(const half8*)&As[(w * 16 + m) * 136 + ks * 32 + q * 8];
            #pragma unroll
            for (int ot = 0; ot < 4; ot++) {
                half8 b = *(const half8*)&Bs[(ot * 16 + m) * 136 + ks * 32 + q * 8];
                acc[ot] = __builtin_amdgcn_mfma_f32_16x16x32_f16(a, b, acc[ot], 0, 0, 0);
            }
        }
        #pragma unroll
        for (int ot = 0; ot < 4; ot++) {
            int col = oseg * 64 + ot * 16 + m;
            float sbv = sb[col];
            #pragma unroll
            for (int rr = 0; rr < 4; rr++) {
                int rowi = iblk * 64 + w * 16 + q * 4 + rr;
                node0b[(size_t)rowi * HID + col] = f2h(acc[ot][rr] + sbv);
            }
        }
    } else {
        // Wt[lh][o][k] = f16(gW[lh][k][o]) via LDS tile transpose
        int g = bx - 1152; int lh = g >> 3, kt = g & 7;
        if (g == 0 && t < NB) out[t] = fc2b[0];   // init for khead2 atomics
        float* tile = smf;   // [64][65]
        const float4* src = (const float4*)(gW + ((size_t)lh * HID + kt * 64) * HD);
        #pragma unroll
        for (int rep = 0; rep < 4; rep++) {
            int f = rep * 256 + t;
            float4 v = src[f];
            int row = f >> 4, col = (f & 15) * 4;
            float* d = tile + row * 65 + col;
            d[0] = v.x; d[1] = v.y; d[2] = v.z; d[3] = v.w;
        }
        __syncthreads();
        int o = t >> 2, ks = (t & 3) * 16;
        us pk[16];
        #pragma unroll
        for (int j = 0; j < 16; j++) pk[j] = f2h(tile[(ks + j) * 65 + o]);
        us* dst = Wt + (size_t)lh * HD * HID + (size_t)o * HID + kt * 64 + ks;
        *(uint4*)dst = *(uint4*)pk;
        *(uint4*)(dst + 8) = *(uint4*)&pk[8];
    }
}

// ============ shared GEMM body: 64x64 tile, BK=64, dbuf, distance-2 global pipeline =====
__device__ __forceinline__ void gemm_body(const us* __restrict__ A, const us* __restrict__ W,
                                          const float* __restrict__ gav,
                                          us* __restrict__ outT, us* __restrict__ outR,
                                          float* __restrict__ esO, float* __restrict__ edO,
                                          int iblk, int b, int h, int t, us* sm) {
    us* As = sm;              // [2][64*72]
    us* Bs = sm + 2 * 4608;   // [2][64*72]
    int row = t >> 2, ks = t & 3;
    int l = t & 63, w = t >> 6, m = l & 15, q = l >> 4;
    size_t arow0 = (size_t)(b * NT + iblk * 64);
    const us* ar = A + (arow0 + row) * HID + ks * 16;
    const us* br = W + ((size_t)(h * HD + row)) * HID + ks * 16;
    f32x4 acc[4];
    #pragma unroll
    for (int ot = 0; ot < 4; ot++) acc[ot] = (f32x4){0.f, 0.f, 0.f, 0.f};
    {
        uint4 x0 = *(const uint4*)ar, x1 = *(const uint4*)(ar + 8);
        uint4 y0 = *(const uint4*)br, y1 = *(const uint4*)(br + 8);
        *(uint4*)&As[row * 72 + ks * 16] = x0; *(uint4*)&As[row * 72 + ks * 16 + 8] = x1;
        *(uint4*)&Bs[row * 72 + ks * 16] = y0; *(uint4*)&Bs[row * 72 + ks * 16 + 8] = y1;
    }
    uint4 a0 = *(const uint4*)(ar + 64), a1 = *(const uint4*)(ar + 72);
    uint4 b0 = *(const uint4*)(br + 64), b1 = *(const uint4*)(br + 72);
    for (int it = 0; it < 8; it++) {
        int cur = it & 1, nxt = cur ^ 1;
        uint4 na0, na1, nb0, nb1;
        if (it < 6) {
            int k0 = (it + 2) * 64;
            na0 = *(const uint4*)(ar + k0); na1 = *(const uint4*)(ar + k0 + 8);
            nb0 = *(const uint4*)(br + k0); nb1 = *(const uint4*)(br + k0 + 8);
        }
        __syncthreads();
        if (it < 7) {
            *(uint4*)&As[nxt * 4608 + row * 72 + ks * 16] = a0;
            *(uint4*)&As[nxt * 4608 + row * 72 + ks * 16 + 8] = a1;
            *(uint4*)&Bs[nxt * 4608 + row * 72 + ks * 16] = b0;
            *(uint4*)&Bs[nxt * 4608 + row * 72 + ks * 16 + 8] = b1;
        }
        const us* Ac = As + cur * 4608; const us* Bc = Bs + cur * 4608;
        #pragma unroll
        for (int kt = 0; kt < 2; kt++) {
            half8 av = *(const half8*)&Ac[(w * 16 + m) * 72 + kt * 32 + q * 8];
            #pragma unroll
            for (int ot = 0; ot < 4; ot++) {
                half8 bv = *(const half8*)&Bc[(ot * 16 + m) * 72 + kt * 32 + q * 8];
                acc[ot] = __builtin_amdgcn_mfma_f32_16x16x32_f16(av, bv, acc[ot], 0, 0, 0);
            }
        }
        if (it < 6) { a0 = na0; a1 = na1; b0 = nb0; b1 = nb1; }
    }
    const float* gas = gav + h * 2 * HD;
    float gs[4], gd[4];
    #pragma unroll
    for (int ot = 0; ot < 4; ot++) { gs[ot] = gas[ot * 16 + m]; gd[ot] = gas[HD + ot * 16 + m]; }
    size_t ebase = ((size_t)b * NH + h) * NT + iblk * 64;
    #pragma unroll
    for (int rr = 0; rr < 4; rr++) {
        float s = 0.f, d = 0.f;
        #pragma unroll
        for (int ot = 0; ot < 4; ot++) { float v = acc[ot][rr]; s = fmaf(v, gs[ot], s); d = fmaf(v, gd[ot], d); }
        #pragma unroll
        for (int mask = 1; mask < 16; mask <<= 1) { s += __shfl_xor(s, mask); d += __shfl_xor(d, mask); }
        if (m == 0) {
            int rowi = w * 16 + q * 4 + rr;
            esO[ebase + rowi] = s;
            edO[ebase + rowi] = d;
        }
    }
    #pragma unroll
    for (int ot = 0; ot < 4; ot++) {
        int col = h * HD + ot * 16 + m;
        #pragma unroll
        for (int rr = 0; rr < 4; rr++) {
            int i_loc = w * 16 + q * 4 + rr;
            float v = acc[ot][rr];
            if (outT) outT[(size_t)col * NT + iblk * 64 + i_loc] = f2h(v);
            if (outR) outR[(arow0 + i_loc) * HID + col] = f2h(v);
        }
    }
}

// ============ kphase1: ktw (0-2047, tw*log2e or NaN, f16) | layer-1 GEMM (2048-2175) ====
__global__ __launch_bounds__(256) void kphase1(const float* __restrict__ tm, const int* __restrict__ adj,
                                               const float* __restrict__ part, us* __restrict__ TWb,
                                               const us* __restrict__ node0b, const us* __restrict__ Wt,
                                               const float* __restrict__ ga, us* __restrict__ Ht1,
                                               float* __restrict__ es1, float* __restrict__ ed1) {
    __shared__ __align__(16) us sm[4 * 4608];
    int bx = blockIdx.x, t = threadIdx.x;
    if (bx < 2048) {
        float* red = (float*)sm;
        float m = fmaxf(fmaxf(part[t * 4], part[t * 4 + 1]), fmaxf(part[t * 4 + 2], part[t * 4 + 3]));
        red[t] = m; __syncthreads();
        for (int s = 128; s > 0; s >>= 1) { if (t < s) red[t] = fmaxf(red[t], red[t + s]); __syncthreads(); }
        float tmx = red[0];
        const float C = 0.1f * LOG2E;
        const float NANF = __uint_as_float(0x7FC00000u);
        #pragma unroll
        for (int it = 0; it < 4; it++) {
            size_t idx = (((size_t)bx * 4 + it) * 256 + t) * 4;
            float4 tv = *(const float4*)(tm + idx);
            int4 av = *(const int4*)(adj + idx);
            float w0 = exp2f((tv.x - tmx) * C) * LOG2E;
            float w1 = exp2f((tv.y - tmx) * C) * LOG2E;
            float w2 = exp2f((tv.z - tmx) * C) * LOG2E;
            float w3 = exp2f((tv.w - tmx) * C) * LOG2E;
            w0 = av.x ? w0 : NANF;   // NaN when masked
            w1 = av.y ? w1 : NANF;
            w2 = av.z ? w2 : NANF;
            w3 = av.w ? w3 : NANF;
            uint2 pk;
            pk.x = pkh2(w0, w1);
            pk.y = pkh2(w2, w3);
            *(uint2*)&TWb[idx] = pk;
        }
    } else {
        int g = bx - 2048;
        gemm_body(node0b, Wt, ga, Ht1, nullptr, es1, ed1, g & 15, 0, g >> 4, t, sm);
    }
}

// ============ layer-2 GEMM (XCD-swizzled: b = n&7 so each XCD owns one batch) ===========
__global__ __launch_bounds__(256) void kgemm2(const us* __restrict__ node1b, const us* __restrict__ Wt2,
                                              const float* __restrict__ ga2, us* __restrict__ H2b,
                                              float* __restrict__ es2, float* __restrict__ ed2) {
    __shared__ __align__(16) us sm[4 * 4608];
    int n = blockIdx.x;
    int b = n & 7, k = n >> 3, iblk = k & 15, h = k >> 4;
    gemm_body(node1b, Wt2, ga2, nullptr, H2b, es2, ed2, iblk, b, h, threadIdx.x, sm);
}

// ============ layer-1 attention: E computed on the fly, P in packed fp16 ================
__device__ __forceinline__ unsigned int p_word_fly(unsigned int tw, unsigned int ed, h16x2 es) {
    h16x2 t = __builtin_bit_cast(h16x2, tw);
    h16x2 d = __builtin_bit_cast(h16x2, ed);
    h16x2 e = es + d;                          // v_pk_add_f16
    h16x2 lk = e * (h16)0.2f;                  // v_pk_mul_f16
    h16x2 el = __builtin_elementwise_max(e, lk); // leaky relu (v_pk_max_f16)
    h16x2 mm = t * el;                         // NaN tw -> NaN
    h16x2 p;
    p.x = __ocml_exp2_f16(mm.x);               // v_exp_f16
    p.y = __ocml_exp2_f16(mm.y);
    h16x2 z = {(h16)0.0f, (h16)0.0f};
    h16x2 r = __builtin_elementwise_max(p, z); // maxNum: NaN -> 0
    return __builtin_bit_cast(unsigned int, r);
}

__device__ __forceinline__ void compute_p_fly(uint4 T0, uint4 T1, uint4 D0, uint4 D1, h16x2 es,
                                              uint4& P01, uint4& P23) {
    P01.x = p_word_fly(T0.x, D0.x, es);
    P01.y = p_word_fly(T0.y, D0.y, es);
    P01.z = p_word_fly(T0.z, D0.z, es);
    P01.w = p_word_fly(T0.w, D0.w, es);
    P23.x = p_word_fly(T1.x, D1.x, es);
    P23.y = p_word_fly(T1.y, D1.y, es);
    P23.z = p_word_fly(T1.z, D1.z, es);
    P23.w = p_word_fly(T1.w, D1.w, es);
}

__global__ __launch_bounds__(256) void kattn1(const us* __restrict__ TWb, const us* __restrict__ Ht,
                                              const float* __restrict__ es1, const float* __restrict__ ed1,
                                              us* __restrict__ node1b) {
    int n = blockIdx.x;                       // XCD-swizzle: each XCD owns one batch b
    int b = n & 7, k = n >> 3, iblk = k & 15, h = k >> 4;
    int t = threadIdx.x;
    __shared__ __align__(16) us Ps[2 * 4608];
    __shared__ __align__(16) us Hs[2 * 4608];
    __shared__ __align__(16) us edl[NT];      // ed (f16) for this head
    __shared__ float invl_s[64];
    int i = t >> 2, js = t & 3;
    int l = t & 63, w = t >> 6, m = l & 15, q = l >> 4;
    // stage ed[h] into LDS as f16 pairs
    {
        float4 ev = *(const float4*)&ed1[h * NT + t * 4];
        uint2 pk; pk.x = pkh2(ev.x, ev.y); pk.y = pkh2(ev.z, ev.w);
        *(uint2*)&edl[t * 4] = pk;
    }
    float esf = es1[h * NT + iblk * 64 + i];
    h16 esh = (h16)esf;
    h16x2 esv = {esh, esh};
    const us* twrow = TWb + ((size_t)(b * NT) + iblk * 64 + i) * NT + js * 16;
    const us* htrow = Ht + ((size_t)(h * HD) + i) * NT + js * 16;
    f32x4 acc[4];
    #pragma unroll
    for (int ot = 0; ot < 4; ot++) acc[ot] = (f32x4){0.f, 0.f, 0.f, 0.f};
    f32x4 acc1 = (f32x4){0.f, 0.f, 0.f, 0.f};         // ones-column: row sums of P
    h16 ov = (m == 0) ? (h16)1.0f : (h16)0.0f;         // B[k][0]=1 else 0
    half8 bones = {ov, ov, ov, ov, ov, ov, ov, ov};
    uint4 T0, T1, Hh0, Hh1;
    T0 = *(const uint4*)twrow; T1 = *(const uint4*)(twrow + 8);
    Hh0 = *(const uint4*)htrow; Hh1 = *(const uint4*)(htrow + 8);
    __syncthreads();   // edl ready
    {
        uint4 D0 = *(const uint4*)&edl[js * 16];
        uint4 D1 = *(const uint4*)&edl[js * 16 + 8];
        uint4 p01, p23;
        compute_p_fly(T0, T1, D0, D1, esv, p01, p23);
        us* Pd = Ps + i * 72 + js * 16;
        us* Hd = Hs + i * 72 + js * 16;
        *(uint4*)Pd = p01; *(uint4*)(Pd + 8) = p23;
        *(uint4*)Hd = Hh0; *(uint4*)(Hd + 8) = Hh1;
    }
    T0 = *(const uint4*)(twrow + 64); T1 = *(const uint4*)(twrow + 72);
    Hh0 = *(const uint4*)(htrow + 64); Hh1 = *(const uint4*)(htrow + 72);
    for (int it = 0; it < 16; it++) {
        int cur = it & 1, nxt = cur ^ 1;
        uint4 nT0, nT1, nH0, nH1;
        if (it < 14) {
            int j0 = (it + 2) * 64;
            nT0 = *(const uint4*)(twrow + j0); nT1 = *(const uint4*)(twrow + j0 + 8);
            nH0 = *(const uint4*)(htrow + j0); nH1 = *(const uint4*)(htrow + j0 + 8);
        }
        uint4 p01, p23;
        if (it < 15) {
            int j0 = (it + 1) * 64;
            uint4 D0 = *(const uint4*)&edl[j0 + js * 16];
            uint4 D1 = *(const uint4*)&edl[j0 + js * 16 + 8];
            compute_p_fly(T0, T1, D0, D1, esv, p01, p23);
        }
        __syncthreads();
        if (it < 15) {
            us* Pd = Ps + nxt * 4608 + i * 72 + js * 16;
            us* Hd = Hs + nxt * 4608 + i * 72 + js * 16;
            *(uint4*)Pd = p01; *(uint4*)(Pd + 8) = p23;
            *(uint4*)Hd = Hh0; *(uint4*)(Hd + 8) = Hh1;
        }
        const us* Pc = Ps + cur * 4608; const us* Hc = Hs + cur * 4608;
        #pragma unroll
        for (int kt = 0; kt < 2; kt++) {
            half8 av = *(const half8*)&Pc[(w * 16 + m) * 72 + kt * 32 + q * 8];
            #pragma unroll
            for (int ot = 0; ot < 4; ot++) {
                half8 bv = *(const half8*)&Hc[(ot * 16 + m) * 72 + kt * 32 + q * 8];
                acc[ot] = __builtin_amdgcn_mfma_f32_16x16x32_f16(av, bv, acc[ot], 0, 0, 0);
            }
            acc1 = __builtin_amdgcn_mfma_f32_16x16x32_f16(av, bones, acc1, 0, 0, 0);
        }
        if (it < 14) { T0 = nT0; T1 = nT1; Hh0 = nH0; Hh1 = nH1; }
    }
    if (m == 0) {
        #pragma unroll
        for (int rr = 0; rr < 4; rr++) invl_s[w * 16 + q * 4 + rr] = 1.f / acc1[rr];
    }
    __syncthreads();
    #pragma unroll
    for (int ot = 0; ot < 4; ot++) {
        int col = h * HD + ot * 16 + m;
        #pragma unroll
        for (int rr = 0; rr < 4; rr++) {
            int i_loc = w * 16 + q * 4 + rr;
            float v = acc[ot][rr] * invl_s[i_loc];
            v = v > 0.f ? v : (__expf(v) - 1.f);  // ELU
            node1b[(size_t)(b * NT + iblk * 64 + i_loc) * HID + col] = f2h(v);
        }
    }
}

// ============ layer-2 attention phase A: partial PV over 64-j slices (1024 blocks) ======
__global__ __launch_bounds__(256) void kattn2a(const us* __restrict__ TWb, const us* __restrict__ H2b,
                                               const float* __restrict__ es2, const float* __restrict__ ed2,
                                               const int* __restrict__ topic_ids,
                                               float* __restrict__ ppv, float* __restrict__ pl) {
    int js = blockIdx.x, h = blockIdx.y, b = blockIdx.z;
    int t = threadIdx.x;
    __shared__ float pls[64];
    __shared__ float red[256];
    int qi = topic_ids[b];
    if (t < 64) {
        int j = js * 64 + t;
        float esq = es2[((size_t)b * NH + h) * NT + qi];
        float tw = h2f(TWb[((size_t)(b * NT) + qi) * NT + j]);  // tw*log2e or NaN
        float e = esq + ed2[((size_t)b * NH + h) * NT + j];
        e = fmaxf(e, 0.2f * e) * tw;
        float p = fmaxf(exp2f(e), 0.f);   // NaN -> 0
        pls[t] = p;
        float lsum = p;
        #pragma unroll
        for (int mask = 1; mask < 64; mask <<= 1) lsum += __shfl_xor(lsum, mask);
        if (t == 0) pl[((size_t)b * NH + h) * 16 + js] = lsum;
    }
    __syncthreads();
    int o = t & 63, jg = t >> 6;
    float acc = 0.f;
    const us* hb = H2b + ((size_t)(b * NT) + js * 64 + jg * 16) * HID + h * HD + o;
    #pragma unroll
    for (int jj = 0; jj < 16; jj++)
        acc = fmaf(pls[jg * 16 + jj], h2f(hb[(size_t)jj * HID]), acc);
    red[t] = acc; __syncthreads();
    if (t < 64) {
        float pv = red[t] + red[t + 64] + red[t + 128] + red[t + 192];
        ppv[(((size_t)b * NH + h) * 16 + js) * HD + t] = pv;
    }
}

// ============ khead2: 256 blocks (kseg 32 x b 8); atomicAdd partials into out[b] ========
__global__ __launch_bounds__(256) void khead2(const float* __restrict__ ppv, const float* __restrict__ pl,
                                              const float* __restrict__ attr,
                                              const float* __restrict__ aW, const float* __restrict__ ab,
                                              const float* __restrict__ fc1W, const float* __restrict__ fc1b,
                                              const float* __restrict__ fc2W, float* __restrict__ out) {
    int kseg = blockIdx.x, b = blockIdx.y;
    int t = threadIdx.x;
    __shared__ float comb[HID];
    __shared__ float linv[NH];
    __shared__ float r2[256];
    if (t < NH) {
        float lsum = 0.f;
        #pragma unroll
        for (int js = 0; js < 16; js++) lsum += pl[((size_t)b * NH + t) * 16 + js];
        linv[t] = 1.f / lsum;
    }
    __syncthreads();
    float av = attr[b];
    for (int k = t; k < HID; k += 256) {
        int h = k >> 6, o = k & 63;
        float pv = 0.f;
        #pragma unroll
        for (int js = 0; js < 16; js++) pv += ppv[(((size_t)b * NH + h) * 16 + js) * HD + o];
        float v = pv * linv[h];
        v = v > 0.f ? v : (__expf(v) - 1.f);  // ELU
        comb[k] = v + av * aW[k] + ab[k];
    }
    __syncthreads();
    // 16 fc1 rows per block; 16 threads per row, coalesced scalar reads
    int kk = kseg * 16 + (t >> 4);
    int j = t & 15;
    const float* row = fc1W + (size_t)kk * HID;
    float acc = 0.f;
    #pragma unroll 8
    for (int mi = 0; mi < 32; mi++) {
        int idx = mi * 16 + j;
        acc = fmaf(comb[idx], row[idx], acc);
    }
    #pragma unroll
    for (int mask = 1; mask < 16; mask <<= 1) acc += __shfl_xor(acc, mask);
    float partv = 0.f;
    if (j == 0) {
        float hk = fmaxf(acc + fc1b[kk], 0.f);
        partv = hk * fc2W[kk];
    }
    r2[t] = partv; __syncthreads();
    for (int s = 128; s > 0; s >>= 1) { if (t < s) r2[t] += r2[t + s]; __syncthreads(); }
    if (t == 0) atomicAdd(&out[b], r2[0]);
}

extern "C" void kernel_launch(void* const* d_in, const int* in_sizes, int n_in,
                              void* d_out, int out_size, void* d_ws, size_t ws_size,
                              hipStream_t stream) {
    const int*   topic_ids = (const int*)d_in[0];
    const int*   adj       = (const int*)d_in[1];
    const float* tm        = (const float*)d_in[2];
    const float* attr      = (const float*)d_in[3];
    const float* emb       = (const float*)d_in[4];
    const float* sW        = (const float*)d_in[5];
    const float* sb        = (const float*)d_in[6];
    const float* aW        = (const float*)d_in[7];
    const float* ab        = (const float*)d_in[8];
    const float* gW        = (const float*)d_in[9];   // (2,8,512,64)
    const float* ga        = (const float*)d_in[10];  // (2,8,128,1)
    const float* fc1W      = (const float*)d_in[11];
    const float* fc1b      = (const float*)d_in[12];
    const float* fc2W      = (const float*)d_in[13];
    const float* fc2b      = (const float*)d_in[14];
    float* out = (float*)d_out;

    char* p = (char*)d_ws;
    us* TWb    = (us*)p; p += sizeof(us) * (size_t)NB * NT * NT;        // 16.8 MB
    us* node0b = (us*)p; p += sizeof(us) * (size_t)NT * HID;            // 1 MB
    us* Wt     = (us*)p; p += sizeof(us) * (size_t)2 * NH * HD * HID;   // 1 MB
    us* Ht1    = (us*)p; p += sizeof(us) * (size_t)HID * NT;            // 1 MB
    us* node1b = (us*)p; p += sizeof(us) * (size_t)NB * NT * HID;       // 8 MB
    us* H2b    = (us*)p; p += sizeof(us) * (size_t)NB * NT * HID;       // 8 MB
    float* es1  = (float*)p; p += sizeof(float) * NH * NT;
    float* ed1  = (float*)p; p += sizeof(float) * NH * NT;
    float* es2  = (float*)p; p += sizeof(float) * NB * NH * NT;
    float* ed2  = (float*)p; p += sizeof(float) * NB * NH * NT;
    float* ppv  = (float*)p; p += sizeof(float) * NB * NH * 16 * HD;
    float* pl   = (float*)p; p += sizeof(float) * NB * NH * 16;
    float* part = (float*)p; p += sizeof(float) * 1024;

    kprep<<<1280, 256, 0, stream>>>(tm, part, emb, sW, sb, node0b, gW, Wt, fc2b, out);
    kphase1<<<2176, 256, 0, stream>>>(tm, adj, part, TWb, node0b, Wt, ga, Ht1, es1, ed1);
    kattn1<<<1024, 256, 0, stream>>>(TWb, Ht1, es1, ed1, node1b);
    kgemm2<<<1024, 256, 0, stream>>>(node1b, Wt + (size_t)NH * HD * HID,
                                     ga + NH * 2 * HD, H2b, es2, ed2);
    kattn2a<<<dim3(16, NH, NB), 256, 0, stream>>>(TWb, H2b, es2, ed2, topic_ids, ppv, pl);
    khead2<<<dim3(32, NB), 256, 0, stream>>>(ppv, pl, attr, aW, ab, fc1W, fc1b, fc2W, out);
}

// Round 5
// 186.891 us; speedup vs baseline: 1.0694x; 1.0054x over previous
//
#include <hip/hip_runtime.h>

#define NT 1024      // N_TOPICS
#define TD 128       // TOPIC_DIM
#define HID 512      // HIDDEN
#define NH 8         // N_HEADS
#define HD 64        // HEAD_DIM
#define NB 8         // BATCH

typedef unsigned short us;
typedef _Float16 h16;
typedef h16 half8 __attribute__((ext_vector_type(8)));
typedef h16 h16x2 __attribute__((ext_vector_type(2)));
typedef float f32x4 __attribute__((ext_vector_type(4)));

#define LOG2E 1.44269504f

extern "C" __device__ _Float16 __ocml_exp2_f16(_Float16);

__device__ __forceinline__ us f2h(float x) { return __builtin_bit_cast(us, (h16)x); }
__device__ __forceinline__ float h2f(us s) { return (float)__builtin_bit_cast(h16, s); }
// pack two f32 -> two f16 in one v_cvt_pkrtz_f16_f32
__device__ __forceinline__ unsigned int pkh2(float a, float b) {
    auto v = __builtin_amdgcn_cvt_pkrtz(a, b);
    return __builtin_bit_cast(unsigned int, v);
}

// ============ kprep: kmax (0-1023) | node0 MFMA GEMM (1024-1151) | gW transpose (1152-1279)
//              block 1152 also initializes out[b] = fc2b[0] for khead2's atomics
__global__ __launch_bounds__(256) void kprep(const float* __restrict__ tm, float* __restrict__ part,
                                             const float* __restrict__ emb, const float* __restrict__ sW,
                                             const float* __restrict__ sb, us* __restrict__ node0b,
                                             const float* __restrict__ gW, us* __restrict__ Wt,
                                             const float* __restrict__ fc2b, float* __restrict__ out) {
    __shared__ __align__(16) float smf[8768];   // 35 KB shared by branches
    int bx = blockIdx.x, t = threadIdx.x;
    if (bx < 1024) {
        const float4* tm4 = (const float4*)tm;
        size_t base = (size_t)bx * 256 + t;
        float m = -1e30f;
        #pragma unroll
        for (int k = 0; k < 8; k++) {
            float4 v = tm4[base + (size_t)k * 262144];
            m = fmaxf(m, fmaxf(fmaxf(v.x, v.y), fmaxf(v.z, v.w)));
        }
        smf[t] = m; __syncthreads();
        for (int s = 128; s > 0; s >>= 1) { if (t < s) smf[t] = fmaxf(smf[t], smf[t + s]); __syncthreads(); }
        if (t == 0) part[bx] = smf[0];
    } else if (bx < 1152) {
        // node0 = emb @ sW^T + sb via MFMA. block: (iblk 16) x (oseg 8); K=128, one barrier.
        int g = bx - 1024; int iblk = g & 15, oseg = g >> 4;
        us* As = (us*)smf;              // [64][136]
        us* Bs = (us*)smf + 64 * 136;   // [64][136]
        const float4* esrc = (const float4*)(emb + (size_t)iblk * 64 * TD);
        const float4* wsrc = (const float4*)(sW + (size_t)oseg * 64 * TD);
        #pragma unroll
        for (int rep = 0; rep < 8; rep++) {
            int f = rep * 256 + t;
            int row = f >> 5, c4 = f & 31;
            float4 av = esrc[f];
            float4 bv = wsrc[f];
            uint2 pa, pb;
            pa.x = pkh2(av.x, av.y); pa.y = pkh2(av.z, av.w);
            pb.x = pkh2(bv.x, bv.y); pb.y = pkh2(bv.z, bv.w);
            *(uint2*)&As[row * 136 + c4 * 4] = pa;
            *(uint2*)&Bs[row * 136 + c4 * 4] = pb;
        }
        __syncthreads();
        int l = t & 63, w = t >> 6, m = l & 15, q = l >> 4;
        f32x4 acc[4];
        #pragma unroll
        for (int ot = 0; ot < 4; ot++) acc[ot] = (f32x4){0.f, 0.f, 0.f, 0.f};
        #pragma unroll
        for (int ks = 0; ks < 4; ks++) {
            half8 a = *(const half8*)&As[(w * 16 + m) * 136 + ks * 32 + q * 8];
            #pragma unroll
            for (int ot = 0; ot < 4; ot++) {
                half8 b = *(const half8*)&Bs[(ot * 16 + m) * 136 + ks * 32 + q * 8];
                acc[ot] = __builtin_amdgcn_mfma_f32_16x16x32_f16(a, b, acc[ot], 0, 0, 0);
            }
        }
        #pragma unroll
        for (int ot = 0; ot < 4; ot++) {
            int col = oseg * 64 + ot * 16 + m;
            float sbv = sb[col];
            #pragma unroll
            for (int rr = 0; rr < 4; rr++) {
                int rowi = iblk * 64 + w * 16 + q * 4 + rr;
                node0b[(size_t)rowi * HID + col] = f2h(acc[ot][rr] + sbv);
            }
        }
    } else {
        // Wt[lh][o][k] = f16(gW[lh][k][o]) via LDS tile transpose
        int g = bx - 1152; int lh = g >> 3, kt = g & 7;
        if (g == 0 && t < NB) out[t] = fc2b[0];   // init for khead2 atomics
        float* tile = smf;   // [64][65]
        const float4* src = (const float4*)(gW + ((size_t)lh * HID + kt * 64) * HD);
        #pragma unroll
        for (int rep = 0; rep < 4; rep++) {
            int f = rep * 256 + t;
            float4 v = src[f];
            int row = f >> 4, col = (f & 15) * 4;
            float* d = tile + row * 65 + col;
            d[0] = v.x; d[1] = v.y; d[2] = v.z; d[3] = v.w;
        }
        __syncthreads();
        int o = t >> 2, ks = (t & 3) * 16;
        us pk[16];
        #pragma unroll
        for (int j = 0; j < 16; j++) pk[j] = f2h(tile[(ks + j) * 65 + o]);
        us* dst = Wt + (size_t)lh * HD * HID + (size_t)o * HID + kt * 64 + ks;
        *(uint4*)dst = *(uint4*)pk;
        *(uint4*)(dst + 8) = *(uint4*)&pk[8];
    }
}

// ============ shared GEMM body: 64x64 tile, BK=64, dbuf, distance-2 global pipeline =====
__device__ __forceinline__ void gemm_body(const us* __restrict__ A, const us* __restrict__ W,
                                          const float* __restrict__ gav,
                                          us* __restrict__ outT, us* __restrict__ outR,
                                          float* __restrict__ esO, float* __restrict__ edO,
                                          int iblk, int b, int h, int t, us* sm) {
    us* As = sm;              // [2][64*72]
    us* Bs = sm + 2 * 4608;   // [2][64*72]
    int row = t >> 2, ks = t & 3;
    int l = t & 63, w = t >> 6, m = l & 15, q = l >> 4;
    size_t arow0 = (size_t)(b * NT + iblk * 64);
    const us* ar = A + (arow0 + row) * HID + ks * 16;
    const us* br = W + ((size_t)(h * HD + row)) * HID + ks * 16;
    f32x4 acc[4];
    #pragma unroll
    for (int ot = 0; ot < 4; ot++) acc[ot] = (f32x4){0.f, 0.f, 0.f, 0.f};
    {
        uint4 x0 = *(const uint4*)ar, x1 = *(const uint4*)(ar + 8);
        uint4 y0 = *(const uint4*)br, y1 = *(const uint4*)(br + 8);
        *(uint4*)&As[row * 72 + ks * 16] = x0; *(uint4*)&As[row * 72 + ks * 16 + 8] = x1;
        *(uint4*)&Bs[row * 72 + ks * 16] = y0; *(uint4*)&Bs[row * 72 + ks * 16 + 8] = y1;
    }
    uint4 a0 = *(const uint4*)(ar + 64), a1 = *(const uint4*)(ar + 72);
    uint4 b0 = *(const uint4*)(br + 64), b1 = *(const uint4*)(br + 72);
    for (int it = 0; it < 8; it++) {
        int cur = it & 1, nxt = cur ^ 1;
        uint4 na0, na1, nb0, nb1;
        if (it < 6) {
            int k0 = (it + 2) * 64;
            na0 = *(const uint4*)(ar + k0); na1 = *(const uint4*)(ar + k0 + 8);
            nb0 = *(const uint4*)(br + k0); nb1 = *(const uint4*)(br + k0 + 8);
        }
        __syncthreads();
        if (it < 7) {
            *(uint4*)&As[nxt * 4608 + row * 72 + ks * 16] = a0;
            *(uint4*)&As[nxt * 4608 + row * 72 + ks * 16 + 8] = a1;
            *(uint4*)&Bs[nxt * 4608 + row * 72 + ks * 16] = b0;
            *(uint4*)&Bs[nxt * 4608 + row * 72 + ks * 16 + 8] = b1;
        }
        const us* Ac = As + cur * 4608; const us* Bc = Bs + cur * 4608;
        #pragma unroll
        for (int kt = 0; kt < 2; kt++) {
            half8 av = *(const half8*)&Ac[(w * 16 + m) * 72 + kt * 32 + q * 8];
            #pragma unroll
            for (int ot = 0; ot < 4; ot++) {
                half8 bv = *(const half8*)&Bc[(ot * 16 + m) * 72 + kt * 32 + q * 8];
                acc[ot] = __builtin_amdgcn_mfma_f32_16x16x32_f16(av, bv, acc[ot], 0, 0, 0);
            }
        }
        if (it < 6) { a0 = na0; a1 = na1; b0 = nb0; b1 = nb1; }
    }
    const float* gas = gav + h * 2 * HD;
    float gs[4], gd[4];
    #pragma unroll
    for (int ot = 0; ot < 4; ot++) { gs[ot] = gas[ot * 16 + m]; gd[ot] = gas[HD + ot * 16 + m]; }
    size_t ebase = ((size_t)b * NH + h) * NT + iblk * 64;
    #pragma unroll
    for (int rr = 0; rr < 4; rr++) {
        float s = 0.f, d = 0.f;
        #pragma unroll
        for (int ot = 0; ot < 4; ot++) { float v = acc[ot][rr]; s = fmaf(v, gs[ot], s); d = fmaf(v, gd[ot], d); }
        #pragma unroll
        for (int mask = 1; mask < 16; mask <<= 1) { s += __shfl_xor(s, mask); d += __shfl_xor(d, mask); }
        if (m == 0) {
            int rowi = w * 16 + q * 4 + rr;
            esO[ebase + rowi] = s;
            edO[ebase + rowi] = d;
        }
    }
    #pragma unroll
    for (int ot = 0; ot < 4; ot++) {
        int col = h * HD + ot * 16 + m;
        #pragma unroll
        for (int rr = 0; rr < 4; rr++) {
            int i_loc = w * 16 + q * 4 + rr;
            float v = acc[ot][rr];
            if (outT) outT[(size_t)col * NT + iblk * 64 + i_loc] = f2h(v);
            if (outR) outR[(arow0 + i_loc) * HID + col] = f2h(v);
        }
    }
}

// ============ kphase1: ktw (0-2047, tw*log2e or NaN, f16) | layer-1 GEMM (2048-2175) ====
__global__ __launch_bounds__(256) void kphase1(const float* __restrict__ tm, const int* __restrict__ adj,
                                               const float* __restrict__ part, us* __restrict__ TWb,
                                               const us* __restrict__ node0b, const us* __restrict__ Wt,
                                               const float* __restrict__ ga, us* __restrict__ Ht1,
                                               float* __restrict__ es1, float* __restrict__ ed1) {
    __shared__ __align__(16) us sm[4 * 4608];
    int bx = blockIdx.x, t = threadIdx.x;
    if (bx < 2048) {
        float* red = (float*)sm;
        float m = fmaxf(fmaxf(part[t * 4], part[t * 4 + 1]), fmaxf(part[t * 4 + 2], part[t * 4 + 3]));
        red[t] = m; __syncthreads();
        for (int s = 128; s > 0; s >>= 1) { if (t < s) red[t] = fmaxf(red[t], red[t + s]); __syncthreads(); }
        float tmx = red[0];
        const float C = 0.1f * LOG2E;
        const float NANF = __uint_as_float(0x7FC00000u);
        #pragma unroll
        for (int it = 0; it < 4; it++) {
            size_t idx = (((size_t)bx * 4 + it) * 256 + t) * 4;
            float4 tv = *(const float4*)(tm + idx);
            int4 av = *(const int4*)(adj + idx);
            float w0 = exp2f((tv.x - tmx) * C) * LOG2E;
            float w1 = exp2f((tv.y - tmx) * C) * LOG2E;
            float w2 = exp2f((tv.z - tmx) * C) * LOG2E;
            float w3 = exp2f((tv.w - tmx) * C) * LOG2E;
            w0 = av.x ? w0 : NANF;   // NaN when masked
            w1 = av.y ? w1 : NANF;
            w2 = av.z ? w2 : NANF;
            w3 = av.w ? w3 : NANF;
            uint2 pk;
            pk.x = pkh2(w0, w1);
            pk.y = pkh2(w2, w3);
            *(uint2*)&TWb[idx] = pk;
        }
    } else {
        int g = bx - 2048;
        gemm_body(node0b, Wt, ga, Ht1, nullptr, es1, ed1, g & 15, 0, g >> 4, t, sm);
    }
}

// ============ layer-2 GEMM (XCD-swizzled: b = n&7 so each XCD owns one batch) ===========
__global__ __launch_bounds__(256) void kgemm2(const us* __restrict__ node1b, const us* __restrict__ Wt2,
                                              const float* __restrict__ ga2, us* __restrict__ H2b,
                                              float* __restrict__ es2, float* __restrict__ ed2) {
    __shared__ __align__(16) us sm[4 * 4608];
    int n = blockIdx.x;
    int b = n & 7, k = n >> 3, iblk = k & 15, h = k >> 4;
    gemm_body(node1b, Wt2, ga2, nullptr, H2b, es2, ed2, iblk, b, h, threadIdx.x, sm);
}

// ============ layer-1 attention: P in A-fragment registers, H-only LDS dbuf =============
__device__ __forceinline__ unsigned int p_word_fly(unsigned int tw, unsigned int ed, h16x2 es) {
    h16x2 t = __builtin_bit_cast(h16x2, tw);
    h16x2 d = __builtin_bit_cast(h16x2, ed);
    h16x2 e = es + d;                          // v_pk_add_f16
    h16x2 lk = e * (h16)0.2f;                  // v_pk_mul_f16
    h16x2 el = __builtin_elementwise_max(e, lk); // leaky relu (v_pk_max_f16)
    h16x2 mm = t * el;                         // NaN tw -> NaN
    h16x2 p;
    p.x = __ocml_exp2_f16(mm.x);               // v_exp_f16
    p.y = __ocml_exp2_f16(mm.y);
    h16x2 z = {(h16)0.0f, (h16)0.0f};
    h16x2 r = __builtin_elementwise_max(p, z); // maxNum: NaN -> 0
    return __builtin_bit_cast(unsigned int, r);
}

__device__ __forceinline__ half8 p_frag(uint4 T, uint4 D, h16x2 es) {
    uint4 r;
    r.x = p_word_fly(T.x, D.x, es);
    r.y = p_word_fly(T.y, D.y, es);
    r.z = p_word_fly(T.z, D.z, es);
    r.w = p_word_fly(T.w, D.w, es);
    return __builtin_bit_cast(half8, r);
}

__global__ __launch_bounds__(256) void kattn1(const us* __restrict__ TWb, const us* __restrict__ Ht,
                                              const float* __restrict__ es1, const float* __restrict__ ed1,
                                              us* __restrict__ node1b) {
    int n = blockIdx.x;               // 512 blocks; b=n&7 -> one batch per XCD
    int b = n & 7, k = n >> 3;
    int i2 = k & 7, h = k >> 3;       // 128-row tile i2, head h
    int t = threadIdx.x;
    __shared__ __align__(16) us Hs[2][64 * 72];
    __shared__ __align__(16) us edl[NT];
    __shared__ float invl_s[128];
    int l = t & 63, w = t >> 6, m = l & 15, q = l >> 4;
    // stage ed[h] into LDS as f16 pairs
    {
        float4 ev = *(const float4*)&ed1[h * NT + t * 4];
        uint2 pk; pk.x = pkh2(ev.x, ev.y); pk.y = pkh2(ev.z, ev.w);
        *(uint2*)&edl[t * 4] = pk;
    }
    int rowA = i2 * 128 + w * 32 + m;          // tile A row; tile B = +16
    h16 eA = (h16)es1[h * NT + rowA];
    h16 eB = (h16)es1[h * NT + rowA + 16];
    h16x2 esvA = {eA, eA}, esvB = {eB, eB};
    const us* twA = TWb + ((size_t)(b * NT) + rowA) * NT + q * 8;
    const us* twB = twA + (size_t)16 * NT;
    int hr = t >> 2, js = t & 3;               // H staging: o-row hr, j-quarter js
    const us* htrow = Ht + ((size_t)(h * HD) + hr) * NT + js * 16;
    f32x4 acc[2][4];
    #pragma unroll
    for (int ti = 0; ti < 2; ti++)
        #pragma unroll
        for (int ot = 0; ot < 4; ot++) acc[ti][ot] = (f32x4){0.f, 0.f, 0.f, 0.f};
    f32x4 acc1[2] = {(f32x4){0.f, 0.f, 0.f, 0.f}, (f32x4){0.f, 0.f, 0.f, 0.f}};
    h16 ov = (m == 0) ? (h16)1.0f : (h16)0.0f;  // ones column
    half8 bones = {ov, ov, ov, ov, ov, ov, ov, ov};
    // prologue: stage H tile0, prefetch H tile1 + TW tile0
    uint4 H0 = *(const uint4*)htrow, H1 = *(const uint4*)(htrow + 8);
    *(uint4*)&Hs[0][hr * 72 + js * 16] = H0;
    *(uint4*)&Hs[0][hr * 72 + js * 16 + 8] = H1;
    H0 = *(const uint4*)(htrow + 64); H1 = *(const uint4*)(htrow + 72);
    uint4 TA0 = *(const uint4*)twA,        TA1 = *(const uint4*)(twA + 32);
    uint4 TB0 = *(const uint4*)twB,        TB1 = *(const uint4*)(twB + 32);
    __syncthreads();   // edl + Hs[0] ready
    for (int it = 0; it < 16; it++) {
        int cur = it & 1, nxt = cur ^ 1;
        int j0 = it * 64;
        uint4 nH0, nH1, nA0, nA1, nB0, nB1;
        if (it < 14) {
            nH0 = *(const uint4*)(htrow + j0 + 128);
            nH1 = *(const uint4*)(htrow + j0 + 136);
        }
        if (it < 15) {
            nA0 = *(const uint4*)(twA + j0 + 64);  nA1 = *(const uint4*)(twA + j0 + 96);
            nB0 = *(const uint4*)(twB + j0 + 64);  nB1 = *(const uint4*)(twB + j0 + 96);
        }
        // P fragments directly in A-operand layout
        uint4 D0 = *(const uint4*)&edl[j0 + q * 8];
        uint4 D1 = *(const uint4*)&edl[j0 + 32 + q * 8];
        half8 pA0 = p_frag(TA0, D0, esvA);
        half8 pA1 = p_frag(TA1, D1, esvA);
        half8 pB0 = p_frag(TB0, D0, esvB);
        half8 pB1 = p_frag(TB1, D1, esvB);
        __syncthreads();
        if (it < 15) {
            *(uint4*)&Hs[nxt][hr * 72 + js * 16] = H0;
            *(uint4*)&Hs[nxt][hr * 72 + js * 16 + 8] = H1;
        }
        const us* Hc = Hs[cur];
        #pragma unroll
        for (int ot = 0; ot < 4; ot++) {
            half8 bv0 = *(const half8*)&Hc[(ot * 16 + m) * 72 + q * 8];
            half8 bv1 = *(const half8*)&Hc[(ot * 16 + m) * 72 + 32 + q * 8];
            acc[0][ot] = __builtin_amdgcn_mfma_f32_16x16x32_f16(pA0, bv0, acc[0][ot], 0, 0, 0);
            acc[0][ot] = __builtin_amdgcn_mfma_f32_16x16x32_f16(pA1, bv1, acc[0][ot], 0, 0, 0);
            acc[1][ot] = __builtin_amdgcn_mfma_f32_16x16x32_f16(pB0, bv0, acc[1][ot], 0, 0, 0);
            acc[1][ot] = __builtin_amdgcn_mfma_f32_16x16x32_f16(pB1, bv1, acc[1][ot], 0, 0, 0);
        }
        acc1[0] = __builtin_amdgcn_mfma_f32_16x16x32_f16(pA0, bones, acc1[0], 0, 0, 0);
        acc1[0] = __builtin_amdgcn_mfma_f32_16x16x32_f16(pA1, bones, acc1[0], 0, 0, 0);
        acc1[1] = __builtin_amdgcn_mfma_f32_16x16x32_f16(pB0, bones, acc1[1], 0, 0, 0);
        acc1[1] = __builtin_amdgcn_mfma_f32_16x16x32_f16(pB1, bones, acc1[1], 0, 0, 0);
        if (it < 14) { H0 = nH0; H1 = nH1; }
        if (it < 15) { TA0 = nA0; TA1 = nA1; TB0 = nB0; TB1 = nB1; }
    }
    if (m == 0) {
        #pragma unroll
        for (int rr = 0; rr < 4; rr++) {
            invl_s[w * 32 + q * 4 + rr]      = 1.f / acc1[0][rr];
            invl_s[w * 32 + 16 + q * 4 + rr] = 1.f / acc1[1][rr];
        }
    }
    __syncthreads();
    size_t rbase = (size_t)(b * NT + i2 * 128);
    #pragma unroll
    for (int ti = 0; ti < 2; ti++) {
        #pragma unroll
        for (int ot = 0; ot < 4; ot++) {
            int col = h * HD + ot * 16 + m;
            #pragma unroll
            for (int rr = 0; rr < 4; rr++) {
                int rloc = w * 32 + ti * 16 + q * 4 + rr;
                float v = acc[ti][ot][rr] * invl_s[rloc];
                v = v > 0.f ? v : (__expf(v) - 1.f);  // ELU
                node1b[(rbase + rloc) * HID + col] = f2h(v);
            }
        }
    }
}

// ============ layer-2 attention phase A: partial PV over 64-j slices (1024 blocks) ======
__global__ __launch_bounds__(256) void kattn2a(const us* __restrict__ TWb, const us* __restrict__ H2b,
                                               const float* __restrict__ es2, const float* __restrict__ ed2,
                                               const int* __restrict__ topic_ids,
                                               float* __restrict__ ppv, float* __restrict__ pl) {
    int js = blockIdx.x, h = blockIdx.y, b = blockIdx.z;
    int t = threadIdx.x;
    __shared__ float pls[64];
    __shared__ float red[256];
    int qi = topic_ids[b];
    if (t < 64) {
        int j = js * 64 + t;
        float esq = es2[((size_t)b * NH + h) * NT + qi];
        float tw = h2f(TWb[((size_t)(b * NT) + qi) * NT + j]);  // tw*log2e or NaN
        float e = esq + ed2[((size_t)b * NH + h) * NT + j];
        e = fmaxf(e, 0.2f * e) * tw;
        float p = fmaxf(exp2f(e), 0.f);   // NaN -> 0
        pls[t] = p;
        float lsum = p;
        #pragma unroll
        for (int mask = 1; mask < 64; mask <<= 1) lsum += __shfl_xor(lsum, mask);
        if (t == 0) pl[((size_t)b * NH + h) * 16 + js] = lsum;
    }
    __syncthreads();
    int o = t & 63, jg = t >> 6;
    float acc = 0.f;
    const us* hb = H2b + ((size_t)(b * NT) + js * 64 + jg * 16) * HID + h * HD + o;
    #pragma unroll
    for (int jj = 0; jj < 16; jj++)
        acc = fmaf(pls[jg * 16 + jj], h2f(hb[(size_t)jj * HID]), acc);
    red[t] = acc; __syncthreads();
    if (t < 64) {
        float pv = red[t] + red[t + 64] + red[t + 128] + red[t + 192];
        ppv[(((size_t)b * NH + h) * 16 + js) * HD + t] = pv;
    }
}

// ============ khead2: 256 blocks (kseg 32 x b 8); atomicAdd partials into out[b] ========
__global__ __launch_bounds__(256) void khead2(const float* __restrict__ ppv, const float* __restrict__ pl,
                                              const float* __restrict__ attr,
                                              const float* __restrict__ aW, const float* __restrict__ ab,
                                              const float* __restrict__ fc1W, const float* __restrict__ fc1b,
                                              const float* __restrict__ fc2W, float* __restrict__ out) {
    int kseg = blockIdx.x, b = blockIdx.y;
    int t = threadIdx.x;
    __shared__ float comb[HID];
    __shared__ float linv[NH];
    __shared__ float r2[256];
    if (t < NH) {
        float lsum = 0.f;
        #pragma unroll
        for (int js = 0; js < 16; js++) lsum += pl[((size_t)b * NH + t) * 16 + js];
        linv[t] = 1.f / lsum;
    }
    __syncthreads();
    float av = attr[b];
    for (int k = t; k < HID; k += 256) {
        int h = k >> 6, o = k & 63;
        float pv = 0.f;
        #pragma unroll
        for (int js = 0; js < 16; js++) pv += ppv[(((size_t)b * NH + h) * 16 + js) * HD + o];
        float v = pv * linv[h];
        v = v > 0.f ? v : (__expf(v) - 1.f);  // ELU
        comb[k] = v + av * aW[k] + ab[k];
    }
    __syncthreads();
    // 16 fc1 rows per block; 16 threads per row, coalesced scalar reads
    int kk = kseg * 16 + (t >> 4);
    int j = t & 15;
    const float* row = fc1W + (size_t)kk * HID;
    float acc = 0.f;
    #pragma unroll 8
    for (int mi = 0; mi < 32; mi++) {
        int idx = mi * 16 + j;
        acc = fmaf(comb[idx], row[idx], acc);
    }
    #pragma unroll
    for (int mask = 1; mask < 16; mask <<= 1) acc += __shfl_xor(acc, mask);
    float partv = 0.f;
    if (j == 0) {
        float hk = fmaxf(acc + fc1b[kk], 0.f);
        partv = hk * fc2W[kk];
    }
    r2[t] = partv; __syncthreads();
    for (int s = 128; s > 0; s >>= 1) { if (t < s) r2[t] += r2[t + s]; __syncthreads(); }
    if (t == 0) atomicAdd(&out[b], r2[0]);
}

extern "C" void kernel_launch(void* const* d_in, const int* in_sizes, int n_in,
                              void* d_out, int out_size, void* d_ws, size_t ws_size,
                              hipStream_t stream) {
    const int*   topic_ids = (const int*)d_in[0];
    const int*   adj       = (const int*)d_in[1];
    const float* tm        = (const float*)d_in[2];
    const float* attr      = (const float*)d_in[3];
    const float* emb       = (const float*)d_in[4];
    const float* sW        = (const float*)d_in[5];
    const float* sb        = (const float*)d_in[6];
    const float* aW        = (const float*)d_in[7];
    const float* ab        = (const float*)d_in[8];
    const float* gW        = (const float*)d_in[9];   // (2,8,512,64)
    const float* ga        = (const float*)d_in[10];  // (2,8,128,1)
    const float* fc1W      = (const float*)d_in[11];
    const float* fc1b      = (const float*)d_in[12];
    const float* fc2W      = (const float*)d_in[13];
    const float* fc2b      = (const float*)d_in[14];
    float* out = (float*)d_out;

    char* p = (char*)d_ws;
    us* TWb    = (us*)p; p += sizeof(us) * (size_t)NB * NT * NT;        // 16.8 MB
    us* node0b = (us*)p; p += sizeof(us) * (size_t)NT * HID;            // 1 MB
    us* Wt     = (us*)p; p += sizeof(us) * (size_t)2 * NH * HD * HID;   // 1 MB
    us* Ht1    = (us*)p; p += sizeof(us) * (size_t)HID * NT;            // 1 MB
    us* node1b = (us*)p; p += sizeof(us) * (size_t)NB * NT * HID;       // 8 MB
    us* H2b    = (us*)p; p += sizeof(us) * (size_t)NB * NT * HID;       // 8 MB
    float* es1  = (float*)p; p += sizeof(float) * NH * NT;
    float* ed1  = (float*)p; p += sizeof(float) * NH * NT;
    float* es2  = (float*)p; p += sizeof(float) * NB * NH * NT;
    float* ed2  = (float*)p; p += sizeof(float) * NB * NH * NT;
    float* ppv  = (float*)p; p += sizeof(float) * NB * NH * 16 * HD;
    float* pl   = (float*)p; p += sizeof(float) * NB * NH * 16;
    float* part = (float*)p; p += sizeof(float) * 1024;

    kprep<<<1280, 256, 0, stream>>>(tm, part, emb, sW, sb, node0b, gW, Wt, fc2b, out);
    kphase1<<<2176, 256, 0, stream>>>(tm, adj, part, TWb, node0b, Wt, ga, Ht1, es1, ed1);
    kattn1<<<512, 256, 0, stream>>>(TWb, Ht1, es1, ed1, node1b);
    kgemm2<<<1024, 256, 0, stream>>>(node1b, Wt + (size_t)NH * HD * HID,
                                     ga + NH * 2 * HD, H2b, es2, ed2);
    kattn2a<<<dim3(16, NH, NB), 256, 0, stream>>>(TWb, H2b, es2, ed2, topic_ids, ppv, pl);
    khead2<<<dim3(32, NB), 256, 0, stream>>>(ppv, pl, attr, aW, ab, fc1W, fc1b, fc2W, out);
}

// Round 7
// 179.260 us; speedup vs baseline: 1.1149x; 1.0426x over previous
//
#include <hip/hip_runtime.h>

#define NT 1024      // N_TOPICS
#define TD 128       // TOPIC_DIM
#define HID 512      // HIDDEN
#define NH 8         // N_HEADS
#define HD 64        // HEAD_DIM
#define NB 8         // BATCH

typedef unsigned short us;
typedef _Float16 h16;
typedef h16 half8 __attribute__((ext_vector_type(8)));
typedef h16 h16x2 __attribute__((ext_vector_type(2)));
typedef float f32x4 __attribute__((ext_vector_type(4)));

#define LOG2E 1.44269504f

extern "C" __device__ _Float16 __ocml_exp2_f16(_Float16);

__device__ __forceinline__ us f2h(float x) { return __builtin_bit_cast(us, (h16)x); }
__device__ __forceinline__ float h2f(us s) { return (float)__builtin_bit_cast(h16, s); }
// pack two f32 -> two f16 in one v_cvt_pkrtz_f16_f32
__device__ __forceinline__ unsigned int pkh2(float a, float b) {
    auto v = __builtin_amdgcn_cvt_pkrtz(a, b);
    return __builtin_bit_cast(unsigned int, v);
}

// ============ kprep: fused max-scan + TWu write (0-1023) | node0 MFMA GEMM (1024-1151)
//              | gW transpose (1152-1279; block 1152 inits out[b])
// TWu[b,i,j] = f16(exp2(tm*0.1*log2e)*log2e) or NaN where adj==0.
// Full tw = TWu * s with s = exp2(-tmax*0.1*log2e), folded into consumers (leaky is
// positively homogeneous, so s folds into es/ed).
__global__ __launch_bounds__(256) void kprep(const float* __restrict__ tm, const int* __restrict__ adj,
                                             float* __restrict__ part, us* __restrict__ TWb,
                                             const float* __restrict__ emb, const float* __restrict__ sW,
                                             const float* __restrict__ sb, us* __restrict__ node0b,
                                             const float* __restrict__ gW, us* __restrict__ Wt,
                                             const float* __restrict__ fc2b, float* __restrict__ out) {
    __shared__ __align__(16) float smf[8768];   // 35 KB shared by branches
    int bx = blockIdx.x, t = threadIdx.x;
    if (bx < 1024) {
        const float4* tm4 = (const float4*)tm;
        const int4* ad4 = (const int4*)adj;
        size_t base = (size_t)bx * 256 + t;
        const float C = 0.1f * LOG2E;
        const float NANF = __uint_as_float(0x7FC00000u);
        float m = -1e30f;
        #pragma unroll
        for (int k = 0; k < 8; k++) {
            size_t fi = base + (size_t)k * 262144;
            float4 v = tm4[fi];
            int4 av = ad4[fi];
            m = fmaxf(m, fmaxf(fmaxf(v.x, v.y), fmaxf(v.z, v.w)));
            float w0 = exp2f(v.x * C) * LOG2E;
            float w1 = exp2f(v.y * C) * LOG2E;
            float w2 = exp2f(v.z * C) * LOG2E;
            float w3 = exp2f(v.w * C) * LOG2E;
            w0 = av.x ? w0 : NANF;
            w1 = av.y ? w1 : NANF;
            w2 = av.z ? w2 : NANF;
            w3 = av.w ? w3 : NANF;
            uint2 pk;
            pk.x = pkh2(w0, w1);
            pk.y = pkh2(w2, w3);
            *(uint2*)&TWb[fi * 4] = pk;
        }
        smf[t] = m; __syncthreads();
        for (int s = 128; s > 0; s >>= 1) { if (t < s) smf[t] = fmaxf(smf[t], smf[t + s]); __syncthreads(); }
        if (t == 0) part[bx] = smf[0];
    } else if (bx < 1152) {
        // node0 = emb @ sW^T + sb via MFMA. block: (iblk 16) x (oseg 8); K=128, one barrier.
        int g = bx - 1024; int iblk = g & 15, oseg = g >> 4;
        us* As = (us*)smf;              // [64][136]
        us* Bs = (us*)smf + 64 * 136;   // [64][136]
        const float4* esrc = (const float4*)(emb + (size_t)iblk * 64 * TD);
        const float4* wsrc = (const float4*)(sW + (size_t)oseg * 64 * TD);
        #pragma unroll
        for (int rep = 0; rep < 8; rep++) {
            int f = rep * 256 + t;
            int row = f >> 5, c4 = f & 31;
            float4 av = esrc[f];
            float4 bv = wsrc[f];
            uint2 pa, pb;
            pa.x = pkh2(av.x, av.y); pa.y = pkh2(av.z, av.w);
            pb.x = pkh2(bv.x, bv.y); pb.y = pkh2(bv.z, bv.w);
            *(uint2*)&As[row * 136 + c4 * 4] = pa;
            *(uint2*)&Bs[row * 136 + c4 * 4] = pb;
        }
        __syncthreads();
        int l = t & 63, w = t >> 6, m = l & 15, q = l >> 4;
        f32x4 acc[4];
        #pragma unroll
        for (int ot = 0; ot < 4; ot++) acc[ot] = (f32x4){0.f, 0.f, 0.f, 0.f};
        #pragma unroll
        for (int ks = 0; ks < 4; ks++) {
            half8 a = *(const half8*)&As[(w * 16 + m) * 136 + ks * 32 + q * 8];
            #pragma unroll
            for (int ot = 0; ot < 4; ot++) {
                half8 b = *(const half8*)&Bs[(ot * 16 + m) * 136 + ks * 32 + q * 8];
                acc[ot] = __builtin_amdgcn_mfma_f32_16x16x32_f16(a, b, acc[ot], 0, 0, 0);
            }
        }
        #pragma unroll
        for (int ot = 0; ot < 4; ot++) {
            int col = oseg * 64 + ot * 16 + m;
            float sbv = sb[col];
            #pragma unroll
            for (int rr = 0; rr < 4; rr++) {
                int rowi = iblk * 64 + w * 16 + q * 4 + rr;
                node0b[(size_t)rowi * HID + col] = f2h(acc[ot][rr] + sbv);
            }
        }
    } else {
        // Wt[lh][o][k] = f16(gW[lh][k][o]) via LDS tile transpose; lh in [0,16), kt in [0,8)
        int g = bx - 1152; int lh = g >> 3, kt = g & 7;
        if (g == 0 && t < NB) out[t] = fc2b[0];   // init for khead2 atomics
        float* tile = smf;   // [64][65]
        const float4* src = (const float4*)(gW + ((size_t)lh * HID + kt * 64) * HD);
        #pragma unroll
        for (int rep = 0; rep < 4; rep++) {
            int f = rep * 256 + t;
            float4 v = src[f];
            int row = f >> 4, col = (f & 15) * 4;
            float* d = tile + row * 65 + col;
            d[0] = v.x; d[1] = v.y; d[2] = v.z; d[3] = v.w;
        }
        __syncthreads();
        int o = t >> 2, ks = (t & 3) * 16;
        us pk[16];
        #pragma unroll
        for (int j = 0; j < 16; j++) pk[j] = f2h(tile[(ks + j) * 65 + o]);
        us* dst = Wt + (size_t)lh * HD * HID + (size_t)o * HID + kt * 64 + ks;
        *(uint4*)dst = *(uint4*)pk;
        *(uint4*)(dst + 8) = *(uint4*)&pk[8];
    }
}

// ============ shared GEMM body: 64x64 tile, BK=64, dbuf, distance-2 global pipeline =====
__device__ __forceinline__ void gemm_body(const us* __restrict__ A, const us* __restrict__ W,
                                          const float* __restrict__ gav,
                                          us* __restrict__ outT, us* __restrict__ outR,
                                          float* __restrict__ esO, float* __restrict__ edO,
                                          int iblk, int b, int h, int t, us* sm) {
    us* As = sm;              // [2][64*72]
    us* Bs = sm + 2 * 4608;   // [2][64*72]
    int row = t >> 2, ks = t & 3;
    int l = t & 63, w = t >> 6, m = l & 15, q = l >> 4;
    size_t arow0 = (size_t)(b * NT + iblk * 64);
    const us* ar = A + (arow0 + row) * HID + ks * 16;
    const us* br = W + ((size_t)(h * HD + row)) * HID + ks * 16;
    f32x4 acc[4];
    #pragma unroll
    for (int ot = 0; ot < 4; ot++) acc[ot] = (f32x4){0.f, 0.f, 0.f, 0.f};
    {
        uint4 x0 = *(const uint4*)ar, x1 = *(const uint4*)(ar + 8);
        uint4 y0 = *(const uint4*)br, y1 = *(const uint4*)(br + 8);
        *(uint4*)&As[row * 72 + ks * 16] = x0; *(uint4*)&As[row * 72 + ks * 16 + 8] = x1;
        *(uint4*)&Bs[row * 72 + ks * 16] = y0; *(uint4*)&Bs[row * 72 + ks * 16 + 8] = y1;
    }
    uint4 a0 = *(const uint4*)(ar + 64), a1 = *(const uint4*)(ar + 72);
    uint4 b0 = *(const uint4*)(br + 64), b1 = *(const uint4*)(br + 72);
    for (int it = 0; it < 8; it++) {
        int cur = it & 1, nxt = cur ^ 1;
        uint4 na0, na1, nb0, nb1;
        if (it < 6) {
            int k0 = (it + 2) * 64;
            na0 = *(const uint4*)(ar + k0); na1 = *(const uint4*)(ar + k0 + 8);
            nb0 = *(const uint4*)(br + k0); nb1 = *(const uint4*)(br + k0 + 8);
        }
        __syncthreads();
        if (it < 7) {
            *(uint4*)&As[nxt * 4608 + row * 72 + ks * 16] = a0;
            *(uint4*)&As[nxt * 4608 + row * 72 + ks * 16 + 8] = a1;
            *(uint4*)&Bs[nxt * 4608 + row * 72 + ks * 16] = b0;
            *(uint4*)&Bs[nxt * 4608 + row * 72 + ks * 16 + 8] = b1;
        }
        const us* Ac = As + cur * 4608; const us* Bc = Bs + cur * 4608;
        #pragma unroll
        for (int kt = 0; kt < 2; kt++) {
            half8 av = *(const half8*)&Ac[(w * 16 + m) * 72 + kt * 32 + q * 8];
            #pragma unroll
            for (int ot = 0; ot < 4; ot++) {
                half8 bv = *(const half8*)&Bc[(ot * 16 + m) * 72 + kt * 32 + q * 8];
                acc[ot] = __builtin_amdgcn_mfma_f32_16x16x32_f16(av, bv, acc[ot], 0, 0, 0);
            }
        }
        if (it < 6) { a0 = na0; a1 = na1; b0 = nb0; b1 = nb1; }
    }
    const float* gas = gav + h * 2 * HD;
    float gs[4], gd[4];
    #pragma unroll
    for (int ot = 0; ot < 4; ot++) { gs[ot] = gas[ot * 16 + m]; gd[ot] = gas[HD + ot * 16 + m]; }
    size_t ebase = ((size_t)b * NH + h) * NT + iblk * 64;
    #pragma unroll
    for (int rr = 0; rr < 4; rr++) {
        float s = 0.f, d = 0.f;
        #pragma unroll
        for (int ot = 0; ot < 4; ot++) { float v = acc[ot][rr]; s = fmaf(v, gs[ot], s); d = fmaf(v, gd[ot], d); }
        #pragma unroll
        for (int mask = 1; mask < 16; mask <<= 1) { s += __shfl_xor(s, mask); d += __shfl_xor(d, mask); }
        if (m == 0) {
            int rowi = w * 16 + q * 4 + rr;
            esO[ebase + rowi] = s;
            edO[ebase + rowi] = d;
        }
    }
    #pragma unroll
    for (int ot = 0; ot < 4; ot++) {
        int col = h * HD + ot * 16 + m;
        #pragma unroll
        for (int rr = 0; rr < 4; rr++) {
            int i_loc = w * 16 + q * 4 + rr;
            float v = acc[ot][rr];
            if (outT) outT[(size_t)col * NT + iblk * 64 + i_loc] = f2h(v);
            if (outR) outR[(arow0 + i_loc) * HID + col] = f2h(v);
        }
    }
}

// ============ layer-1 GEMM (128 blocks) ================================================
__global__ __launch_bounds__(256) void kgemm1(const us* __restrict__ node0b, const us* __restrict__ Wt,
                                              const float* __restrict__ ga, us* __restrict__ Ht1,
                                              float* __restrict__ es1, float* __restrict__ ed1) {
    __shared__ __align__(16) us sm[4 * 4608];
    int g = blockIdx.x;
    gemm_body(node0b, Wt, ga, Ht1, nullptr, es1, ed1, g & 15, 0, g >> 4, threadIdx.x, sm);
}

// ============ layer-2 GEMM (XCD-swizzled: b = n&7 so each XCD owns one batch) ===========
__global__ __launch_bounds__(256) void kgemm2(const us* __restrict__ node1b, const us* __restrict__ Wt2,
                                              const float* __restrict__ ga2, us* __restrict__ H2b,
                                              float* __restrict__ es2, float* __restrict__ ed2) {
    __shared__ __align__(16) us sm[4 * 4608];
    int n = blockIdx.x;
    int b = n & 7, k = n >> 3, iblk = k & 15, h = k >> 4;
    gemm_body(node1b, Wt2, ga2, nullptr, H2b, es2, ed2, iblk, b, h, threadIdx.x, sm);
}

// ============ layer-1 attention: P in A-fragment registers, H-only LDS dbuf =============
__device__ __forceinline__ unsigned int p_word_fly(unsigned int tw, unsigned int ed, h16x2 es) {
    h16x2 t = __builtin_bit_cast(h16x2, tw);
    h16x2 d = __builtin_bit_cast(h16x2, ed);
    h16x2 e = es + d;                          // v_pk_add_f16 (es,ed pre-scaled by s)
    h16x2 lk = e * (h16)0.2f;                  // v_pk_mul_f16
    h16x2 el = __builtin_elementwise_max(e, lk); // leaky relu (v_pk_max_f16)
    h16x2 mm = t * el;                         // NaN tw -> NaN
    h16x2 p;
    p.x = __ocml_exp2_f16(mm.x);               // v_exp_f16
    p.y = __ocml_exp2_f16(mm.y);
    h16x2 z = {(h16)0.0f, (h16)0.0f};
    h16x2 r = __builtin_elementwise_max(p, z); // maxNum: NaN -> 0
    return __builtin_bit_cast(unsigned int, r);
}

__device__ __forceinline__ half8 p_frag(uint4 T, uint4 D, h16x2 es) {
    uint4 r;
    r.x = p_word_fly(T.x, D.x, es);
    r.y = p_word_fly(T.y, D.y, es);
    r.z = p_word_fly(T.z, D.z, es);
    r.w = p_word_fly(T.w, D.w, es);
    return __builtin_bit_cast(half8, r);
}

__global__ __launch_bounds__(256) void kattn1(const us* __restrict__ TWb, const us* __restrict__ Ht,
                                              const float* __restrict__ es1, const float* __restrict__ ed1,
                                              const float* __restrict__ part, us* __restrict__ node1b) {
    int n = blockIdx.x;               // 512 blocks; b=n&7 -> one batch per XCD
    int b = n & 7, k = n >> 3;
    int i2 = k & 7, h = k >> 3;       // 128-row tile i2, head h
    int t = threadIdx.x;
    __shared__ __align__(16) us Hs[2][64 * 72];
    __shared__ __align__(16) us edl[NT];
    __shared__ float invl_s[128];
    __shared__ float reds[256];
    int l = t & 63, w = t >> 6, m = l & 15, q = l >> 4;
    // reduce part -> tmax -> sfac = exp(-0.1*tmax)
    {
        float pm = fmaxf(fmaxf(part[t * 4], part[t * 4 + 1]), fmaxf(part[t * 4 + 2], part[t * 4 + 3]));
        reds[t] = pm; __syncthreads();
        for (int s = 128; s > 0; s >>= 1) { if (t < s) reds[t] = fmaxf(reds[t], reds[t + s]); __syncthreads(); }
    }
    float sfac = exp2f(-reds[0] * (0.1f * LOG2E));
    // stage ed[h]*sfac into LDS as f16 pairs
    {
        float4 ev = *(const float4*)&ed1[h * NT + t * 4];
        uint2 pk; pk.x = pkh2(ev.x * sfac, ev.y * sfac); pk.y = pkh2(ev.z * sfac, ev.w * sfac);
        *(uint2*)&edl[t * 4] = pk;
    }
    int rowA = i2 * 128 + w * 32 + m;          // tile A row; tile B = +16
    h16 eA = (h16)(es1[h * NT + rowA] * sfac);
    h16 eB = (h16)(es1[h * NT + rowA + 16] * sfac);
    h16x2 esvA = {eA, eA}, esvB = {eB, eB};
    const us* twA = TWb + ((size_t)(b * NT) + rowA) * NT + q * 8;
    const us* twB = twA + (size_t)16 * NT;
    int hr = t >> 2, js = t & 3;               // H staging: o-row hr, j-quarter js
    const us* htrow = Ht + ((size_t)(h * HD) + hr) * NT + js * 16;
    f32x4 acc[2][4];
    #pragma unroll
    for (int ti = 0; ti < 2; ti++)
        #pragma unroll
        for (int ot = 0; ot < 4; ot++) acc[ti][ot] = (f32x4){0.f, 0.f, 0.f, 0.f};
    f32x4 acc1[2] = {(f32x4){0.f, 0.f, 0.f, 0.f}, (f32x4){0.f, 0.f, 0.f, 0.f}};
    h16 ov = (m == 0) ? (h16)1.0f : (h16)0.0f;  // ones column
    half8 bones = {ov, ov, ov, ov, ov, ov, ov, ov};
    // prologue: stage H tile0, prefetch H tile1 + TW tile0
    uint4 H0 = *(const uint4*)htrow, H1 = *(const uint4*)(htrow + 8);
    *(uint4*)&Hs[0][hr * 72 + js * 16] = H0;
    *(uint4*)&Hs[0][hr * 72 + js * 16 + 8] = H1;
    H0 = *(const uint4*)(htrow + 64); H1 = *(const uint4*)(htrow + 72);
    uint4 TA0 = *(const uint4*)twA,        TA1 = *(const uint4*)(twA + 32);
    uint4 TB0 = *(const uint4*)twB,        TB1 = *(const uint4*)(twB + 32);
    __syncthreads();   // edl + Hs[0] ready
    for (int it = 0; it < 16; it++) {
        int cur = it & 1, nxt = cur ^ 1;
        int j0 = it * 64;
        uint4 nH0, nH1, nA0, nA1, nB0, nB1;
        if (it < 14) {
            nH0 = *(const uint4*)(htrow + j0 + 128);
            nH1 = *(const uint4*)(htrow + j0 + 136);
        }
        if (it < 15) {
            nA0 = *(const uint4*)(twA + j0 + 64);  nA1 = *(const uint4*)(twA + j0 + 96);
            nB0 = *(const uint4*)(twB + j0 + 64);  nB1 = *(const uint4*)(twB + j0 + 96);
        }
        // P fragments directly in A-operand layout
        uint4 D0 = *(const uint4*)&edl[j0 + q * 8];
        uint4 D1 = *(const uint4*)&edl[j0 + 32 + q * 8];
        half8 pA0 = p_frag(TA0, D0, esvA);
        half8 pA1 = p_frag(TA1, D1, esvA);
        half8 pB0 = p_frag(TB0, D0, esvB);
        half8 pB1 = p_frag(TB1, D1, esvB);
        __syncthreads();
        if (it < 15) {
            *(uint4*)&Hs[nxt][hr * 72 + js * 16] = H0;
            *(uint4*)&Hs[nxt][hr * 72 + js * 16 + 8] = H1;
        }
        const us* Hc = Hs[cur];
        #pragma unroll
        for (int ot = 0; ot < 4; ot++) {
            half8 bv0 = *(const half8*)&Hc[(ot * 16 + m) * 72 + q * 8];
            half8 bv1 = *(const half8*)&Hc[(ot * 16 + m) * 72 + 32 + q * 8];
            acc[0][ot] = __builtin_amdgcn_mfma_f32_16x16x32_f16(pA0, bv0, acc[0][ot], 0, 0, 0);
            acc[0][ot] = __builtin_amdgcn_mfma_f32_16x16x32_f16(pA1, bv1, acc[0][ot], 0, 0, 0);
            acc[1][ot] = __builtin_amdgcn_mfma_f32_16x16x32_f16(pB0, bv0, acc[1][ot], 0, 0, 0);
            acc[1][ot] = __builtin_amdgcn_mfma_f32_16x16x32_f16(pB1, bv1, acc[1][ot], 0, 0, 0);
        }
        acc1[0] = __builtin_amdgcn_mfma_f32_16x16x32_f16(pA0, bones, acc1[0], 0, 0, 0);
        acc1[0] = __builtin_amdgcn_mfma_f32_16x16x32_f16(pA1, bones, acc1[0], 0, 0, 0);
        acc1[1] = __builtin_amdgcn_mfma_f32_16x16x32_f16(pB0, bones, acc1[1], 0, 0, 0);
        acc1[1] = __builtin_amdgcn_mfma_f32_16x16x32_f16(pB1, bones, acc1[1], 0, 0, 0);
        if (it < 14) { H0 = nH0; H1 = nH1; }
        if (it < 15) { TA0 = nA0; TA1 = nA1; TB0 = nB0; TB1 = nB1; }
    }
    if (m == 0) {
        #pragma unroll
        for (int rr = 0; rr < 4; rr++) {
            invl_s[w * 32 + q * 4 + rr]      = 1.f / acc1[0][rr];
            invl_s[w * 32 + 16 + q * 4 + rr] = 1.f / acc1[1][rr];
        }
    }
    __syncthreads();
    size_t rbase = (size_t)(b * NT + i2 * 128);
    #pragma unroll
    for (int ti = 0; ti < 2; ti++) {
        #pragma unroll
        for (int ot = 0; ot < 4; ot++) {
            int col = h * HD + ot * 16 + m;
            #pragma unroll
            for (int rr = 0; rr < 4; rr++) {
                int rloc = w * 32 + ti * 16 + q * 4 + rr;
                float v = acc[ti][ot][rr] * invl_s[rloc];
                v = v > 0.f ? v : (__expf(v) - 1.f);  // ELU
                node1b[(rbase + rloc) * HID + col] = f2h(v);
            }
        }
    }
}

// ============ layer-2 attention phase A: partial PV over 64-j slices (1024 blocks) ======
__global__ __launch_bounds__(256) void kattn2a(const us* __restrict__ TWb, const us* __restrict__ H2b,
                                               const float* __restrict__ es2, const float* __restrict__ ed2,
                                               const int* __restrict__ topic_ids, const float* __restrict__ part,
                                               float* __restrict__ ppv, float* __restrict__ pl) {
    int js = blockIdx.x, h = blockIdx.y, b = blockIdx.z;
    int t = threadIdx.x;
    __shared__ float pls[64];
    __shared__ float red[256];
    int qi = topic_ids[b];
    // reduce part -> sfac
    {
        float pm = fmaxf(fmaxf(part[t * 4], part[t * 4 + 1]), fmaxf(part[t * 4 + 2], part[t * 4 + 3]));
        red[t] = pm; __syncthreads();
        for (int s = 128; s > 0; s >>= 1) { if (t < s) red[t] = fmaxf(red[t], red[t + s]); __syncthreads(); }
    }
    float sfac = exp2f(-red[0] * (0.1f * LOG2E));
    __syncthreads();
    if (t < 64) {
        int j = js * 64 + t;
        float esq = es2[((size_t)b * NH + h) * NT + qi];
        float tw = h2f(TWb[((size_t)(b * NT) + qi) * NT + j]);  // twu*log2e or NaN
        float e = esq + ed2[((size_t)b * NH + h) * NT + j];
        e = fmaxf(e, 0.2f * e) * (tw * sfac);
        float p = fmaxf(exp2f(e), 0.f);   // NaN -> 0
        pls[t] = p;
        float lsum = p;
        #pragma unroll
        for (int mask = 1; mask < 64; mask <<= 1) lsum += __shfl_xor(lsum, mask);
        if (t == 0) pl[((size_t)b * NH + h) * 16 + js] = lsum;
    }
    __syncthreads();
    int o = t & 63, jg = t >> 6;
    float acc = 0.f;
    const us* hb = H2b + ((size_t)(b * NT) + js * 64 + jg * 16) * HID + h * HD + o;
    #pragma unroll
    for (int jj = 0; jj < 16; jj++)
        acc = fmaf(pls[jg * 16 + jj], h2f(hb[(size_t)jj * HID]), acc);
    red[t] = acc; __syncthreads();
    if (t < 64) {
        float pv = red[t] + red[t + 64] + red[t + 128] + red[t + 192];
        ppv[(((size_t)b * NH + h) * 16 + js) * HD + t] = pv;
    }
}

// ============ khead2: 256 blocks (kseg 32 x b 8); atomicAdd partials into out[b] ========
__global__ __launch_bounds__(256) void khead2(const float* __restrict__ ppv, const float* __restrict__ pl,
                                              const float* __restrict__ attr,
                                              const float* __restrict__ aW, const float* __restrict__ ab,
                                              const float* __restrict__ fc1W, const float* __restrict__ fc1b,
                                              const float* __restrict__ fc2W, float* __restrict__ out) {
    int kseg = blockIdx.x, b = blockIdx.y;
    int t = threadIdx.x;
    __shared__ float comb[HID];
    __shared__ float linv[NH];
    __shared__ float r2[256];
    if (t < NH) {
        float lsum = 0.f;
        #pragma unroll
        for (int js = 0; js < 16; js++) lsum += pl[((size_t)b * NH + t) * 16 + js];
        linv[t] = 1.f / lsum;
    }
    __syncthreads();
    float av = attr[b];
    for (int k = t; k < HID; k += 256) {
        int h = k >> 6, o = k & 63;
        float pv = 0.f;
        #pragma unroll
        for (int js = 0; js < 16; js++) pv += ppv[(((size_t)b * NH + h) * 16 + js) * HD + o];
        float v = pv * linv[h];
        v = v > 0.f ? v : (__expf(v) - 1.f);  // ELU
        comb[k] = v + av * aW[k] + ab[k];
    }
    __syncthreads();
    // 16 fc1 rows per block; 16 threads per row, coalesced scalar reads
    int kk = kseg * 16 + (t >> 4);
    int j = t & 15;
    const float* row = fc1W + (size_t)kk * HID;
    float acc = 0.f;
    #pragma unroll 8
    for (int mi = 0; mi < 32; mi++) {
        int idx = mi * 16 + j;
        acc = fmaf(comb[idx], row[idx], acc);
    }
    #pragma unroll
    for (int mask = 1; mask < 16; mask <<= 1) acc += __shfl_xor(acc, mask);
    float partv = 0.f;
    if (j == 0) {
        float hk = fmaxf(acc + fc1b[kk], 0.f);
        partv = hk * fc2W[kk];
    }
    r2[t] = partv; __syncthreads();
    for (int s = 128; s > 0; s >>= 1) { if (t < s) r2[t] += r2[t + s]; __syncthreads(); }
    if (t == 0) atomicAdd(&out[b], r2[0]);
}

extern "C" void kernel_launch(void* const* d_in, const int* in_sizes, int n_in,
                              void* d_out, int out_size, void* d_ws, size_t ws_size,
                              hipStream_t stream) {
    const int*   topic_ids = (const int*)d_in[0];
    const int*   adj       = (const int*)d_in[1];
    const float* tm        = (const float*)d_in[2];
    const float* attr      = (const float*)d_in[3];
    const float* emb       = (const float*)d_in[4];
    const float* sW        = (const float*)d_in[5];
    const float* sb        = (const float*)d_in[6];
    const float* aW        = (const float*)d_in[7];
    const float* ab        = (const float*)d_in[8];
    const float* gW        = (const float*)d_in[9];   // (2,8,512,64)
    const float* ga        = (const float*)d_in[10];  // (2,8,128,1)
    const float* fc1W      = (const float*)d_in[11];
    const float* fc1b      = (const float*)d_in[12];
    const float* fc2W      = (const float*)d_in[13];
    const float* fc2b      = (const float*)d_in[14];
    float* out = (float*)d_out;

    char* p = (char*)d_ws;
    us* TWb    = (us*)p; p += sizeof(us) * (size_t)NB * NT * NT;        // 16.8 MB
    us* node0b = (us*)p; p += sizeof(us) * (size_t)NT * HID;            // 1 MB
    us* Wt     = (us*)p; p += sizeof(us) * (size_t)2 * NH * HD * HID;   // 1 MB
    us* Ht1    = (us*)p; p += sizeof(us) * (size_t)HID * NT;            // 1 MB
    us* node1b = (us*)p; p += sizeof(us) * (size_t)NB * NT * HID;       // 8 MB
    us* H2b    = (us*)p; p += sizeof(us) * (size_t)NB * NT * HID;       // 8 MB
    float* es1  = (float*)p; p += sizeof(float) * NH * NT;
    float* ed1  = (float*)p; p += sizeof(float) * NH * NT;
    float* es2  = (float*)p; p += sizeof(float) * NB * NH * NT;
    float* ed2  = (float*)p; p += sizeof(float) * NB * NH * NT;
    float* ppv  = (float*)p; p += sizeof(float) * NB * NH * 16 * HD;
    float* pl   = (float*)p; p += sizeof(float) * NB * NH * 16;
    float* part = (float*)p; p += sizeof(float) * 1024;

    kprep<<<1280, 256, 0, stream>>>(tm, adj, part, TWb, emb, sW, sb, node0b, gW, Wt, fc2b, out);
    kgemm1<<<128, 256, 0, stream>>>(node0b, Wt, ga, Ht1, es1, ed1);
    kattn1<<<512, 256, 0, stream>>>(TWb, Ht1, es1, ed1, part, node1b);
    kgemm2<<<1024, 256, 0, stream>>>(node1b, Wt + (size_t)NH * HD * HID,
                                     ga + NH * 2 * HD, H2b, es2, ed2);
    kattn2a<<<dim3(16, NH, NB), 256, 0, stream>>>(TWb, H2b, es2, ed2, topic_ids, part, ppv, pl);
    khead2<<<dim3(32, NB), 256, 0, stream>>>(ppv, pl, attr, aW, ab, fc1W, fc1b, fc2W, out);
}

// Round 8
// 176.937 us; speedup vs baseline: 1.1295x; 1.0131x over previous
//
#include <hip/hip_runtime.h>

#define NT 1024      // N_TOPICS
#define TD 128       // TOPIC_DIM
#define HID 512      // HIDDEN
#define NH 8         // N_HEADS
#define HD 64        // HEAD_DIM
#define NB 8         // BATCH

typedef unsigned short us;
typedef _Float16 h16;
typedef h16 half8 __attribute__((ext_vector_type(8)));
typedef h16 h16x2 __attribute__((ext_vector_type(2)));
typedef float f32x4 __attribute__((ext_vector_type(4)));

#define LOG2E 1.44269504f

extern "C" __device__ _Float16 __ocml_exp2_f16(_Float16);

__device__ __forceinline__ us f2h(float x) { return __builtin_bit_cast(us, (h16)x); }
__device__ __forceinline__ float h2f(us s) { return (float)__builtin_bit_cast(h16, s); }
__device__ __forceinline__ unsigned int pkh2(float a, float b) {
    auto v = __builtin_amdgcn_cvt_pkrtz(a, b);
    return __builtin_bit_cast(unsigned int, v);
}

// ============ kprep: fused max-scan + TWu (0-1023) | node0 GEMM (1024-1151)
//              | gW transpose (1152-1279) | VAVS (1280-1343)
// TWu = f16(exp2(tm*0.1*log2e)*log2e) or NaN where adj==0; tw = TWu*sfac.
// VAVS[n][i]: n<8 -> W2_n @ a_dst (for ed2); n>=8 -> W2_(n-8) @ a_src (for es2q).
__global__ __launch_bounds__(256) void kprep(const float* __restrict__ tm, const int* __restrict__ adj,
                                             float* __restrict__ part, us* __restrict__ TWb,
                                             const float* __restrict__ emb, const float* __restrict__ sW,
                                             const float* __restrict__ sb, us* __restrict__ node0b,
                                             const float* __restrict__ gW, us* __restrict__ Wt,
                                             const float* __restrict__ ga, us* __restrict__ VAVS,
                                             const float* __restrict__ fc2b, float* __restrict__ out) {
    __shared__ __align__(16) float smf[8768];
    int bx = blockIdx.x, t = threadIdx.x;
    if (bx < 1024) {
        const float4* tm4 = (const float4*)tm;
        const int4* ad4 = (const int4*)adj;
        size_t base = (size_t)bx * 256 + t;
        const float C = 0.1f * LOG2E;
        const float NANF = __uint_as_float(0x7FC00000u);
        float m = -1e30f;
        #pragma unroll
        for (int k = 0; k < 8; k++) {
            size_t fi = base + (size_t)k * 262144;
            float4 v = tm4[fi];
            int4 av = ad4[fi];
            m = fmaxf(m, fmaxf(fmaxf(v.x, v.y), fmaxf(v.z, v.w)));
            float w0 = exp2f(v.x * C) * LOG2E;
            float w1 = exp2f(v.y * C) * LOG2E;
            float w2 = exp2f(v.z * C) * LOG2E;
            float w3 = exp2f(v.w * C) * LOG2E;
            w0 = av.x ? w0 : NANF;
            w1 = av.y ? w1 : NANF;
            w2 = av.z ? w2 : NANF;
            w3 = av.w ? w3 : NANF;
            uint2 pk;
            pk.x = pkh2(w0, w1);
            pk.y = pkh2(w2, w3);
            *(uint2*)&TWb[fi * 4] = pk;
        }
        smf[t] = m; __syncthreads();
        for (int s = 128; s > 0; s >>= 1) { if (t < s) smf[t] = fmaxf(smf[t], smf[t + s]); __syncthreads(); }
        if (t == 0) part[bx] = smf[0];
    } else if (bx < 1152) {
        int g = bx - 1024; int iblk = g & 15, oseg = g >> 4;
        us* As = (us*)smf;              // [64][136]
        us* Bs = (us*)smf + 64 * 136;
        const float4* esrc = (const float4*)(emb + (size_t)iblk * 64 * TD);
        const float4* wsrc = (const float4*)(sW + (size_t)oseg * 64 * TD);
        #pragma unroll
        for (int rep = 0; rep < 8; rep++) {
            int f = rep * 256 + t;
            int row = f >> 5, c4 = f & 31;
            float4 av = esrc[f];
            float4 bv = wsrc[f];
            uint2 pa, pb;
            pa.x = pkh2(av.x, av.y); pa.y = pkh2(av.z, av.w);
            pb.x = pkh2(bv.x, bv.y); pb.y = pkh2(bv.z, bv.w);
            *(uint2*)&As[row * 136 + c4 * 4] = pa;
            *(uint2*)&Bs[row * 136 + c4 * 4] = pb;
        }
        __syncthreads();
        int l = t & 63, w = t >> 6, m = l & 15, q = l >> 4;
        f32x4 acc[4];
        #pragma unroll
        for (int ot = 0; ot < 4; ot++) acc[ot] = (f32x4){0.f, 0.f, 0.f, 0.f};
        #pragma unroll
        for (int ks = 0; ks < 4; ks++) {
            half8 a = *(const half8*)&As[(w * 16 + m) * 136 + ks * 32 + q * 8];
            #pragma unroll
            for (int ot = 0; ot < 4; ot++) {
                half8 b = *(const half8*)&Bs[(ot * 16 + m) * 136 + ks * 32 + q * 8];
                acc[ot] = __builtin_amdgcn_mfma_f32_16x16x32_f16(a, b, acc[ot], 0, 0, 0);
            }
        }
        #pragma unroll
        for (int ot = 0; ot < 4; ot++) {
            int col = oseg * 64 + ot * 16 + m;
            float sbv = sb[col];
            #pragma unroll
            for (int rr = 0; rr < 4; rr++) {
                int rowi = iblk * 64 + w * 16 + q * 4 + rr;
                node0b[(size_t)rowi * HID + col] = f2h(acc[ot][rr] + sbv);
            }
        }
    } else if (bx < 1280) {
        // Wt[lh][o][k] = f16(gW[lh][k][o]); lh in [0,16), kt in [0,8)
        int g = bx - 1152; int lh = g >> 3, kt = g & 7;
        if (g == 0 && t < NB) out[t] = fc2b[0];
        float* tile = smf;   // [64][65]
        const float4* src = (const float4*)(gW + ((size_t)lh * HID + kt * 64) * HD);
        #pragma unroll
        for (int rep = 0; rep < 4; rep++) {
            int f = rep * 256 + t;
            float4 v = src[f];
            int row = f >> 4, col = (f & 15) * 4;
            float* d = tile + row * 65 + col;
            d[0] = v.x; d[1] = v.y; d[2] = v.z; d[3] = v.w;
        }
        __syncthreads();
        int o = t >> 2, ks = (t & 3) * 16;
        us pk[16];
        #pragma unroll
        for (int j = 0; j < 16; j++) pk[j] = f2h(tile[(ks + j) * 65 + o]);
        us* dst = Wt + (size_t)lh * HD * HID + (size_t)o * HID + kt * 64 + ks;
        *(uint4*)dst = *(uint4*)pk;
        *(uint4*)(dst + 8) = *(uint4*)&pk[8];
    } else {
        // VAVS: 64 blocks: h = g>>3, iseg = g&7; t<128: sel = t>>6 (0: va/dst, 1: vs/src)
        int g = bx - 1280; int h = g >> 3, iseg = g & 7;
        if (t < 128) {
            int sel = t >> 6, il = t & 63;
            int i = iseg * 64 + il;
            const float* W2row = gW + (size_t)NH * HID * HD + ((size_t)h * HID + i) * HD;
            const float* a2 = ga + NH * 2 * HD + h * 2 * HD;
            const float* av = sel ? a2 : (a2 + HD);   // vs uses a_src (0..63), va uses a_dst (64..127)
            float s = 0.f;
            #pragma unroll 8
            for (int o = 0; o < HD; o++) s = fmaf(W2row[o], av[o], s);
            VAVS[(size_t)(sel * 8 + h) * HID + i] = f2h(s);
        }
    }
}

// ============ shared GEMM body (layer-1 only now) =======================================
__device__ __forceinline__ void gemm_body(const us* __restrict__ A, const us* __restrict__ W,
                                          const float* __restrict__ gav,
                                          us* __restrict__ outT,
                                          float* __restrict__ esO, float* __restrict__ edO,
                                          int iblk, int b, int h, int t, us* sm) {
    us* As = sm;              // [2][64*72]
    us* Bs = sm + 2 * 4608;
    int row = t >> 2, ks = t & 3;
    int l = t & 63, w = t >> 6, m = l & 15, q = l >> 4;
    size_t arow0 = (size_t)(b * NT + iblk * 64);
    const us* ar = A + (arow0 + row) * HID + ks * 16;
    const us* br = W + ((size_t)(h * HD + row)) * HID + ks * 16;
    f32x4 acc[4];
    #pragma unroll
    for (int ot = 0; ot < 4; ot++) acc[ot] = (f32x4){0.f, 0.f, 0.f, 0.f};
    {
        uint4 x0 = *(const uint4*)ar, x1 = *(const uint4*)(ar + 8);
        uint4 y0 = *(const uint4*)br, y1 = *(const uint4*)(br + 8);
        *(uint4*)&As[row * 72 + ks * 16] = x0; *(uint4*)&As[row * 72 + ks * 16 + 8] = x1;
        *(uint4*)&Bs[row * 72 + ks * 16] = y0; *(uint4*)&Bs[row * 72 + ks * 16 + 8] = y1;
    }
    uint4 a0 = *(const uint4*)(ar + 64), a1 = *(const uint4*)(ar + 72);
    uint4 b0 = *(const uint4*)(br + 64), b1 = *(const uint4*)(br + 72);
    for (int it = 0; it < 8; it++) {
        int cur = it & 1, nxt = cur ^ 1;
        uint4 na0, na1, nb0, nb1;
        if (it < 6) {
            int k0 = (it + 2) * 64;
            na0 = *(const uint4*)(ar + k0); na1 = *(const uint4*)(ar + k0 + 8);
            nb0 = *(const uint4*)(br + k0); nb1 = *(const uint4*)(br + k0 + 8);
        }
        __syncthreads();
        if (it < 7) {
            *(uint4*)&As[nxt * 4608 + row * 72 + ks * 16] = a0;
            *(uint4*)&As[nxt * 4608 + row * 72 + ks * 16 + 8] = a1;
            *(uint4*)&Bs[nxt * 4608 + row * 72 + ks * 16] = b0;
            *(uint4*)&Bs[nxt * 4608 + row * 72 + ks * 16 + 8] = b1;
        }
        const us* Ac = As + cur * 4608; const us* Bc = Bs + cur * 4608;
        #pragma unroll
        for (int kt = 0; kt < 2; kt++) {
            half8 av = *(const half8*)&Ac[(w * 16 + m) * 72 + kt * 32 + q * 8];
            #pragma unroll
            for (int ot = 0; ot < 4; ot++) {
                half8 bv = *(const half8*)&Bc[(ot * 16 + m) * 72 + kt * 32 + q * 8];
                acc[ot] = __builtin_amdgcn_mfma_f32_16x16x32_f16(av, bv, acc[ot], 0, 0, 0);
            }
        }
        if (it < 6) { a0 = na0; a1 = na1; b0 = nb0; b1 = nb1; }
    }
    const float* gas = gav + h * 2 * HD;
    float gs[4], gd[4];
    #pragma unroll
    for (int ot = 0; ot < 4; ot++) { gs[ot] = gas[ot * 16 + m]; gd[ot] = gas[HD + ot * 16 + m]; }
    size_t ebase = ((size_t)b * NH + h) * NT + iblk * 64;
    #pragma unroll
    for (int rr = 0; rr < 4; rr++) {
        float s = 0.f, d = 0.f;
        #pragma unroll
        for (int ot = 0; ot < 4; ot++) { float v = acc[ot][rr]; s = fmaf(v, gs[ot], s); d = fmaf(v, gd[ot], d); }
        #pragma unroll
        for (int mask = 1; mask < 16; mask <<= 1) { s += __shfl_xor(s, mask); d += __shfl_xor(d, mask); }
        if (m == 0) {
            int rowi = w * 16 + q * 4 + rr;
            esO[ebase + rowi] = s;
            edO[ebase + rowi] = d;
        }
    }
    #pragma unroll
    for (int ot = 0; ot < 4; ot++) {
        int col = h * HD + ot * 16 + m;
        #pragma unroll
        for (int rr = 0; rr < 4; rr++) {
            int i_loc = w * 16 + q * 4 + rr;
            outT[(size_t)col * NT + iblk * 64 + i_loc] = f2h(acc[ot][rr]);
        }
    }
}

// ============ layer-1 GEMM (128 blocks) ================================================
__global__ __launch_bounds__(256) void kgemm1(const us* __restrict__ node0b, const us* __restrict__ Wt,
                                              const float* __restrict__ ga, us* __restrict__ Ht1,
                                              float* __restrict__ es1, float* __restrict__ ed1) {
    __shared__ __align__(16) us sm[4 * 4608];
    int g = blockIdx.x;
    gemm_body(node0b, Wt, ga, Ht1, es1, ed1, g & 15, 0, g >> 4, threadIdx.x, sm);
}

// ============ layer-1 attention (unchanged from R7) ====================================
__device__ __forceinline__ unsigned int p_word_fly(unsigned int tw, unsigned int ed, h16x2 es) {
    h16x2 t = __builtin_bit_cast(h16x2, tw);
    h16x2 d = __builtin_bit_cast(h16x2, ed);
    h16x2 e = es + d;
    h16x2 lk = e * (h16)0.2f;
    h16x2 el = __builtin_elementwise_max(e, lk);
    h16x2 mm = t * el;
    h16x2 p;
    p.x = __ocml_exp2_f16(mm.x);
    p.y = __ocml_exp2_f16(mm.y);
    h16x2 z = {(h16)0.0f, (h16)0.0f};
    h16x2 r = __builtin_elementwise_max(p, z);
    return __builtin_bit_cast(unsigned int, r);
}

__device__ __forceinline__ half8 p_frag(uint4 T, uint4 D, h16x2 es) {
    uint4 r;
    r.x = p_word_fly(T.x, D.x, es);
    r.y = p_word_fly(T.y, D.y, es);
    r.z = p_word_fly(T.z, D.z, es);
    r.w = p_word_fly(T.w, D.w, es);
    return __builtin_bit_cast(half8, r);
}

__global__ __launch_bounds__(256) void kattn1(const us* __restrict__ TWb, const us* __restrict__ Ht,
                                              const float* __restrict__ es1, const float* __restrict__ ed1,
                                              const float* __restrict__ part, us* __restrict__ node1b) {
    int n = blockIdx.x;               // 512 blocks; b=n&7 -> one batch per XCD
    int b = n & 7, k = n >> 3;
    int i2 = k & 7, h = k >> 3;
    int t = threadIdx.x;
    __shared__ __align__(16) us Hs[2][64 * 72];
    __shared__ __align__(16) us edl[NT];
    __shared__ float invl_s[128];
    __shared__ float reds[256];
    int l = t & 63, w = t >> 6, m = l & 15, q = l >> 4;
    {
        float pm = fmaxf(fmaxf(part[t * 4], part[t * 4 + 1]), fmaxf(part[t * 4 + 2], part[t * 4 + 3]));
        reds[t] = pm; __syncthreads();
        for (int s = 128; s > 0; s >>= 1) { if (t < s) reds[t] = fmaxf(reds[t], reds[t + s]); __syncthreads(); }
    }
    float sfac = exp2f(-reds[0] * (0.1f * LOG2E));
    {
        float4 ev = *(const float4*)&ed1[h * NT + t * 4];
        uint2 pk; pk.x = pkh2(ev.x * sfac, ev.y * sfac); pk.y = pkh2(ev.z * sfac, ev.w * sfac);
        *(uint2*)&edl[t * 4] = pk;
    }
    int rowA = i2 * 128 + w * 32 + m;
    h16 eA = (h16)(es1[h * NT + rowA] * sfac);
    h16 eB = (h16)(es1[h * NT + rowA + 16] * sfac);
    h16x2 esvA = {eA, eA}, esvB = {eB, eB};
    const us* twA = TWb + ((size_t)(b * NT) + rowA) * NT + q * 8;
    const us* twB = twA + (size_t)16 * NT;
    int hr = t >> 2, js = t & 3;
    const us* htrow = Ht + ((size_t)(h * HD) + hr) * NT + js * 16;
    f32x4 acc[2][4];
    #pragma unroll
    for (int ti = 0; ti < 2; ti++)
        #pragma unroll
        for (int ot = 0; ot < 4; ot++) acc[ti][ot] = (f32x4){0.f, 0.f, 0.f, 0.f};
    f32x4 acc1[2] = {(f32x4){0.f, 0.f, 0.f, 0.f}, (f32x4){0.f, 0.f, 0.f, 0.f}};
    h16 ov = (m == 0) ? (h16)1.0f : (h16)0.0f;
    half8 bones = {ov, ov, ov, ov, ov, ov, ov, ov};
    uint4 H0 = *(const uint4*)htrow, H1 = *(const uint4*)(htrow + 8);
    *(uint4*)&Hs[0][hr * 72 + js * 16] = H0;
    *(uint4*)&Hs[0][hr * 72 + js * 16 + 8] = H1;
    H0 = *(const uint4*)(htrow + 64); H1 = *(const uint4*)(htrow + 72);
    uint4 TA0 = *(const uint4*)twA,        TA1 = *(const uint4*)(twA + 32);
    uint4 TB0 = *(const uint4*)twB,        TB1 = *(const uint4*)(twB + 32);
    __syncthreads();
    for (int it = 0; it < 16; it++) {
        int cur = it & 1, nxt = cur ^ 1;
        int j0 = it * 64;
        uint4 nH0, nH1, nA0, nA1, nB0, nB1;
        if (it < 14) {
            nH0 = *(const uint4*)(htrow + j0 + 128);
            nH1 = *(const uint4*)(htrow + j0 + 136);
        }
        if (it < 15) {
            nA0 = *(const uint4*)(twA + j0 + 64);  nA1 = *(const uint4*)(twA + j0 + 96);
            nB0 = *(const uint4*)(twB + j0 + 64);  nB1 = *(const uint4*)(twB + j0 + 96);
        }
        uint4 D0 = *(const uint4*)&edl[j0 + q * 8];
        uint4 D1 = *(const uint4*)&edl[j0 + 32 + q * 8];
        half8 pA0 = p_frag(TA0, D0, esvA);
        half8 pA1 = p_frag(TA1, D1, esvA);
        half8 pB0 = p_frag(TB0, D0, esvB);
        half8 pB1 = p_frag(TB1, D1, esvB);
        __syncthreads();
        if (it < 15) {
            *(uint4*)&Hs[nxt][hr * 72 + js * 16] = H0;
            *(uint4*)&Hs[nxt][hr * 72 + js * 16 + 8] = H1;
        }
        const us* Hc = Hs[cur];
        #pragma unroll
        for (int ot = 0; ot < 4; ot++) {
            half8 bv0 = *(const half8*)&Hc[(ot * 16 + m) * 72 + q * 8];
            half8 bv1 = *(const half8*)&Hc[(ot * 16 + m) * 72 + 32 + q * 8];
            acc[0][ot] = __builtin_amdgcn_mfma_f32_16x16x32_f16(pA0, bv0, acc[0][ot], 0, 0, 0);
            acc[0][ot] = __builtin_amdgcn_mfma_f32_16x16x32_f16(pA1, bv1, acc[0][ot], 0, 0, 0);
            acc[1][ot] = __builtin_amdgcn_mfma_f32_16x16x32_f16(pB0, bv0, acc[1][ot], 0, 0, 0);
            acc[1][ot] = __builtin_amdgcn_mfma_f32_16x16x32_f16(pB1, bv1, acc[1][ot], 0, 0, 0);
        }
        acc1[0] = __builtin_amdgcn_mfma_f32_16x16x32_f16(pA0, bones, acc1[0], 0, 0, 0);
        acc1[0] = __builtin_amdgcn_mfma_f32_16x16x32_f16(pA1, bones, acc1[0], 0, 0, 0);
        acc1[1] = __builtin_amdgcn_mfma_f32_16x16x32_f16(pB0, bones, acc1[1], 0, 0, 0);
        acc1[1] = __builtin_amdgcn_mfma_f32_16x16x32_f16(pB1, bones, acc1[1], 0, 0, 0);
        if (it < 14) { H0 = nH0; H1 = nH1; }
        if (it < 15) { TA0 = nA0; TA1 = nA1; TB0 = nB0; TB1 = nB1; }
    }
    if (m == 0) {
        #pragma unroll
        for (int rr = 0; rr < 4; rr++) {
            invl_s[w * 32 + q * 4 + rr]      = 1.f / acc1[0][rr];
            invl_s[w * 32 + 16 + q * 4 + rr] = 1.f / acc1[1][rr];
        }
    }
    __syncthreads();
    size_t rbase = (size_t)(b * NT + i2 * 128);
    #pragma unroll
    for (int ti = 0; ti < 2; ti++) {
        #pragma unroll
        for (int ot = 0; ot < 4; ot++) {
            int col = h * HD + ot * 16 + m;
            #pragma unroll
            for (int rr = 0; rr < 4; rr++) {
                int rloc = w * 32 + ti * 16 + q * 4 + rr;
                float v = acc[ti][ot][rr] * invl_s[rloc];
                v = v > 0.f ? v : (__expf(v) - 1.f);
                node1b[(rbase + rloc) * HID + col] = f2h(v);
            }
        }
    }
}

// ============ kctx: layer-2 attention via PV associativity ==============================
// Per (b, jb): ed[h][j] = n1[j]·va[h] (MFMA), P row-qi slice, partial ctx = P @ n1.
__global__ __launch_bounds__(256) void kctx(const us* __restrict__ TWb, const us* __restrict__ node1b,
                                            const us* __restrict__ VAVS, const float* __restrict__ part,
                                            const int* __restrict__ topic_ids,
                                            float* __restrict__ ctxp, float* __restrict__ pl) {
    int n = blockIdx.x;          // 256: b = n&7, jb = n>>3 (32 rows each)
    int b = n & 7, jb = n >> 3;
    int t = threadIdx.x;
    __shared__ __align__(16) us n1s[32 * 520];
    __shared__ __align__(16) us vvs[16 * 520];
    __shared__ __align__(16) us qrow[HID];
    __shared__ float Ps[8][33];
    __shared__ float es2q[8];
    __shared__ float reds[256];
    int qi = topic_ids[b];
    {
        float pm = fmaxf(fmaxf(part[t * 4], part[t * 4 + 1]), fmaxf(part[t * 4 + 2], part[t * 4 + 3]));
        reds[t] = pm; __syncthreads();
        for (int s = 128; s > 0; s >>= 1) { if (t < s) reds[t] = fmaxf(reds[t], reds[t + s]); __syncthreads(); }
    }
    float sfac = exp2f(-reds[0] * (0.1f * LOG2E));
    {   // stage node1 tile [32][512]
        int row = t >> 3, c = (t & 7) * 64;
        const uint4* src = (const uint4*)(node1b + ((size_t)(b * NT) + jb * 32 + row) * HID + c);
        uint4* dst = (uint4*)&n1s[row * 520 + c];
        #pragma unroll
        for (int k = 0; k < 8; k++) dst[k] = src[k];
    }
    {   // stage VAVS [16][512]
        int row = t >> 4, c = (t & 15) * 32;
        const uint4* src = (const uint4*)(VAVS + (size_t)row * HID + c);
        uint4* dst = (uint4*)&vvs[row * 520 + c];
        dst[0] = src[0]; dst[1] = src[1]; dst[2] = src[2]; dst[3] = src[3];
    }
    if (t < 32) {   // stage node1 row qi
        const uint4* src = (const uint4*)(node1b + ((size_t)(b * NT) + qi) * HID + t * 16);
        *(uint4*)&qrow[t * 16] = src[0];
        *(uint4*)&qrow[t * 16 + 8] = src[1];
    }
    __syncthreads();
    {   // es2q[h] = sum_i qrow[i]*vs[h][i]
        int h = t >> 5, li = t & 31;
        float s = 0.f;
        #pragma unroll 4
        for (int ii = 0; ii < 16; ii++) {
            int i = li * 16 + ii;
            s = fmaf(h2f(qrow[i]), h2f(vvs[(8 + h) * 520 + i]), s);
        }
        #pragma unroll
        for (int mask = 1; mask < 32; mask <<= 1) s += __shfl_xor(s, mask);
        if (li == 0) es2q[h] = s;
    }
    __syncthreads();
    int l = t & 63, w = t >> 6, m = l & 15, q = l >> 4;
    if (w < 2) {   // ed via MFMA: [32 j] x [16 n], K=512
        f32x4 acc = (f32x4){0.f, 0.f, 0.f, 0.f};
        #pragma unroll
        for (int kt = 0; kt < 16; kt++) {
            half8 a = *(const half8*)&n1s[(w * 16 + m) * 520 + kt * 32 + q * 8];
            half8 bv = *(const half8*)&vvs[m * 520 + kt * 32 + q * 8];
            acc = __builtin_amdgcn_mfma_f32_16x16x32_f16(a, bv, acc, 0, 0, 0);
        }
        if (m < 8) {   // P[h=m][j]
            const us* twq = TWb + ((size_t)(b * NT) + qi) * NT + jb * 32;
            float esv = es2q[m];
            #pragma unroll
            for (int r = 0; r < 4; r++) {
                int j = w * 16 + q * 4 + r;
                float e = esv + acc[r];
                e = fmaxf(e, 0.2f * e);
                float twu = h2f(twq[j]);
                float p = fmaxf(exp2f(twu * sfac * e), 0.f);   // NaN -> 0
                Ps[m][j] = p;
            }
        }
    }
    __syncthreads();
    {   // pl[b][h][jb]
        int h = t >> 5, j = t & 31;
        float s = Ps[h][j];
        #pragma unroll
        for (int mask = 1; mask < 32; mask <<= 1) s += __shfl_xor(s, mask);
        if (j == 0) pl[((size_t)b * NH + h) * 32 + jb] = s;
    }
    // partial ctx: thread owns o pair (t*2, t*2+1)
    float ac[8][2];
    #pragma unroll
    for (int h = 0; h < 8; h++) { ac[h][0] = 0.f; ac[h][1] = 0.f; }
    for (int j = 0; j < 32; j++) {
        unsigned int uv = *(const unsigned int*)&n1s[j * 520 + t * 2];
        h16x2 hv = __builtin_bit_cast(h16x2, uv);
        float f0 = (float)hv.x, f1 = (float)hv.y;
        #pragma unroll
        for (int h = 0; h < 8; h++) {
            float p = Ps[h][j];
            ac[h][0] = fmaf(p, f0, ac[h][0]);
            ac[h][1] = fmaf(p, f1, ac[h][1]);
        }
    }
    float* cp = ctxp + (((size_t)b * 32 + jb) * NH) * HID;
    #pragma unroll
    for (int h = 0; h < 8; h++) {
        float2 v; v.x = ac[h][0]; v.y = ac[h][1];
        *(float2*)&cp[h * HID + t * 2] = v;
    }
}

// ============ kcomb: reduce ctx, normalize, @W2 (Wt2), ELU, +attract ====================
__global__ __launch_bounds__(256) void kcomb(const float* __restrict__ ctxp, const float* __restrict__ pl,
                                             const us* __restrict__ Wt2, const float* __restrict__ attr,
                                             const float* __restrict__ aW, const float* __restrict__ ab,
                                             float* __restrict__ comb) {
    int h = blockIdx.x & 7, b = blockIdx.x >> 3;
    int t = threadIdx.x;
    __shared__ float cx[HID];
    __shared__ float ln[1];
    if (t < 32) {
        float s = pl[((size_t)b * NH + h) * 32 + t];
        #pragma unroll
        for (int mask = 1; mask < 32; mask <<= 1) s += __shfl_xor(s, mask);
        if (t == 0) ln[0] = 1.f / s;
    }
    float a0 = 0.f, a1 = 0.f;
    for (int jb = 0; jb < 32; jb++) {
        const float* cp = ctxp + (((size_t)b * 32 + jb) * NH + h) * HID;
        a0 += cp[t]; a1 += cp[t + 256];
    }
    __syncthreads();
    float li = ln[0];
    cx[t] = a0 * li; cx[t + 256] = a1 * li;
    __syncthreads();
    int o2 = t >> 2, ks = t & 3;
    const us* wrow = Wt2 + ((size_t)h * HD + o2) * HID + ks * 128;
    float s = 0.f;
    #pragma unroll 8
    for (int k = 0; k < 128; k++) s = fmaf(cx[ks * 128 + k], h2f(wrow[k]), s);
    s += __shfl_xor(s, 1); s += __shfl_xor(s, 2);
    if (ks == 0) {
        float v = s > 0.f ? s : (__expf(s) - 1.f);   // ELU
        int col = h * HD + o2;
        comb[b * HID + col] = v + attr[b] * aW[col] + ab[col];
    }
}

// ============ kfc: fc1 + relu + fc2; atomicAdd into out[b] ==============================
__global__ __launch_bounds__(256) void kfc(const float* __restrict__ comb,
                                           const float* __restrict__ fc1W, const float* __restrict__ fc1b,
                                           const float* __restrict__ fc2W, float* __restrict__ out) {
    int kseg = blockIdx.x, b = blockIdx.y;
    int t = threadIdx.x;
    __shared__ float cs[HID];
    __shared__ float r2[256];
    cs[t] = comb[b * HID + t];
    cs[t + 256] = comb[b * HID + t + 256];
    __syncthreads();
    int kk = kseg * 16 + (t >> 4);
    int j = t & 15;
    const float* row = fc1W + (size_t)kk * HID;
    float acc = 0.f;
    #pragma unroll 8
    for (int mi = 0; mi < 32; mi++) {
        int idx = mi * 16 + j;
        acc = fmaf(cs[idx], row[idx], acc);
    }
    #pragma unroll
    for (int mask = 1; mask < 16; mask <<= 1) acc += __shfl_xor(acc, mask);
    float partv = 0.f;
    if (j == 0) {
        float hk = fmaxf(acc + fc1b[kk], 0.f);
        partv = hk * fc2W[kk];
    }
    r2[t] = partv; __syncthreads();
    for (int s = 128; s > 0; s >>= 1) { if (t < s) r2[t] += r2[t + s]; __syncthreads(); }
    if (t == 0) atomicAdd(&out[b], r2[0]);
}

extern "C" void kernel_launch(void* const* d_in, const int* in_sizes, int n_in,
                              void* d_out, int out_size, void* d_ws, size_t ws_size,
                              hipStream_t stream) {
    const int*   topic_ids = (const int*)d_in[0];
    const int*   adj       = (const int*)d_in[1];
    const float* tm        = (const float*)d_in[2];
    const float* attr      = (const float*)d_in[3];
    const float* emb       = (const float*)d_in[4];
    const float* sW        = (const float*)d_in[5];
    const float* sb        = (const float*)d_in[6];
    const float* aW        = (const float*)d_in[7];
    const float* ab        = (const float*)d_in[8];
    const float* gW        = (const float*)d_in[9];   // (2,8,512,64)
    const float* ga        = (const float*)d_in[10];  // (2,8,128,1)
    const float* fc1W      = (const float*)d_in[11];
    const float* fc1b      = (const float*)d_in[12];
    const float* fc2W      = (const float*)d_in[13];
    const float* fc2b      = (const float*)d_in[14];
    float* out = (float*)d_out;

    char* p = (char*)d_ws;
    us* TWb    = (us*)p; p += sizeof(us) * (size_t)NB * NT * NT;        // 16.8 MB
    us* node0b = (us*)p; p += sizeof(us) * (size_t)NT * HID;            // 1 MB
    us* Wt     = (us*)p; p += sizeof(us) * (size_t)2 * NH * HD * HID;   // 1 MB
    us* Ht1    = (us*)p; p += sizeof(us) * (size_t)HID * NT;            // 1 MB
    us* node1b = (us*)p; p += sizeof(us) * (size_t)NB * NT * HID;       // 8 MB
    us* VAVS   = (us*)p; p += sizeof(us) * (size_t)16 * HID;            // 16 KB
    float* es1  = (float*)p; p += sizeof(float) * NH * NT;
    float* ed1  = (float*)p; p += sizeof(float) * NH * NT;
    float* ctxp = (float*)p; p += sizeof(float) * (size_t)NB * 32 * NH * HID;  // 4 MB
    float* pl   = (float*)p; p += sizeof(float) * NB * NH * 32;
    float* comb = (float*)p; p += sizeof(float) * NB * HID;
    float* part = (float*)p; p += sizeof(float) * 1024;

    kprep<<<1344, 256, 0, stream>>>(tm, adj, part, TWb, emb, sW, sb, node0b, gW, Wt, ga, VAVS, fc2b, out);
    kgemm1<<<128, 256, 0, stream>>>(node0b, Wt, ga, Ht1, es1, ed1);
    kattn1<<<512, 256, 0, stream>>>(TWb, Ht1, es1, ed1, part, node1b);
    kctx<<<256, 256, 0, stream>>>(TWb, node1b, VAVS, part, topic_ids, ctxp, pl);
    kcomb<<<64, 256, 0, stream>>>(ctxp, pl, Wt + (size_t)NH * HD * HID, attr, aW, ab, comb);
    kfc<<<dim3(32, NB), 256, 0, stream>>>(comb, fc1W, fc1b, fc2W, out);
}